// Round 9
// baseline (3575.972 us; speedup 1.0000x reference)
//
#include <hip/hip_runtime.h>

#define NN    50000
#define DD    128
#define RR    3
#define EE    800000
#define OUTD  64
#define BKT   128                 // nodes per bucket (dst and src binning)
#define NBK   391                 // ceil(NN/BKT)
#define CAP   2560                // per-bucket edge capacity, 4B dst-entries
#define CAPB  2560                // per-bucket edge capacity, 2B src-entries
#define CHUNK 2048                // edges per bin block
#define NCH   391                 // ceil(EE/CHUNK)
#define NSB   782                 // src>>6 bins (50000/64)
#define ALPHA_ 0.5f
#define SLOPE_ 0.01f
#define BETA1_ 0.6931471805599453f   // log(2)
#define BETA2_ 0.4054651081081644f   // log(1.5)

typedef __attribute__((ext_vector_type(8))) short short8;   // 8 bf16 = 4 VGPRs
typedef __attribute__((ext_vector_type(4))) float f32x4;

__device__ __forceinline__ unsigned short f2b(float f) {   // fp32 -> bf16 RNE
    unsigned int u = __builtin_bit_cast(unsigned int, f);
    u += 0x7FFFu + ((u >> 16) & 1u);
    return (unsigned short)(u >> 16);
}
__device__ __forceinline__ unsigned int pack2(float lo, float hi) {
    return (unsigned int)f2b(lo) | ((unsigned int)f2b(hi) << 16);
}
__device__ __forceinline__ float blo(unsigned int w) { return __builtin_bit_cast(float, w << 16); }
__device__ __forceinline__ float bhi(unsigned int w) { return __builtin_bit_cast(float, w & 0xFFFF0000u); }

// ---------------- binning: two LDS bucket-sort phases (by dst>>7, then by src>>7) ----------------
// NO per-edge global atomics. Phase A payload: src(16)|dlocal(7)|bucket(9).
// Phase B payload (ushort): bucket(9)<<7 | slocal(7).
__global__ __launch_bounds__(256) void bin_kernel(
    const int* __restrict__ src, const int* __restrict__ dst,
    int* __restrict__ bcnt_d, int* __restrict__ bcnt_s,
    int* __restrict__ pairs_d, unsigned short* __restrict__ pairs_s)
{
    __shared__ int hist[NBK];
    __shared__ int lbase[NBK];
    __shared__ int gdelta[NBK];
    __shared__ int lcur[NBK];
    __shared__ unsigned int staging[CHUNK];
    unsigned short* staging16 = (unsigned short*)staging;
    const int tid = threadIdx.x;
    const int r = blockIdx.x / NCH;
    const int chunk = blockIdx.x % NCH;
    const int e0 = chunk * CHUNK;
    const int n = min(CHUNK, EE - e0);
    const int* sp = src + (size_t)r * EE + e0;
    const int* dp = dst + (size_t)r * EE + e0;

    // ================= phase A: bin by dst>>7 =================
    for (int i = tid; i < NBK; i += 256) hist[i] = 0;
    __syncthreads();
    for (int i = tid; i < n; i += 256)
        atomicAdd(&hist[dp[i] >> 7], 1);
    __syncthreads();
    if (tid < 64) {
        int carry = 0;
        for (int c0 = 0; c0 < NBK; c0 += 64) {
            const int idx = c0 + tid;
            const int v = (idx < NBK) ? hist[idx] : 0;
            int incl = v;
            #pragma unroll
            for (int d = 1; d < 64; d <<= 1) {
                const int t = __shfl_up(incl, d, 64);
                if (tid >= d) incl += t;
            }
            if (idx < NBK) lbase[idx] = carry + incl - v;
            carry += __shfl(incl, 63, 64);
        }
    }
    __syncthreads();
    for (int b = tid; b < NBK; b += 256) {
        lcur[b] = lbase[b];
        const int h = hist[b];
        if (h > 0) {
            const int gstart = (r * NBK + b) * CAP + atomicAdd(&bcnt_d[r * NBK + b], h);
            gdelta[b] = gstart - lbase[b];
        }
    }
    __syncthreads();
    for (int i = tid; i < n; i += 256) {
        const int d = dp[i];
        const int b = d >> 7;
        const int pos = atomicAdd(&lcur[b], 1);
        staging[pos] = (unsigned int)sp[i] | ((unsigned int)(d & 127) << 16)
                     | ((unsigned int)b << 23);
    }
    __syncthreads();
    for (int j = tid; j < n; j += 256) {
        const unsigned int v = staging[j];
        const int b = v >> 23;
        const int gi = gdelta[b] + j;
        const int lo = gi - (r * NBK + b) * CAP;
        if (lo < CAP) pairs_d[gi] = (int)(v & 0x7FFFFF);
    }
    __syncthreads();

    // ================= phase B: bin by src>>7 (for out-degree counting) =================
    for (int i = tid; i < NBK; i += 256) hist[i] = 0;
    __syncthreads();
    for (int i = tid; i < n; i += 256)
        atomicAdd(&hist[sp[i] >> 7], 1);
    __syncthreads();
    if (tid < 64) {
        int carry = 0;
        for (int c0 = 0; c0 < NBK; c0 += 64) {
            const int idx = c0 + tid;
            const int v = (idx < NBK) ? hist[idx] : 0;
            int incl = v;
            #pragma unroll
            for (int d = 1; d < 64; d <<= 1) {
                const int t = __shfl_up(incl, d, 64);
                if (tid >= d) incl += t;
            }
            if (idx < NBK) lbase[idx] = carry + incl - v;
            carry += __shfl(incl, 63, 64);
        }
    }
    __syncthreads();
    for (int b = tid; b < NBK; b += 256) {
        lcur[b] = lbase[b];
        const int h = hist[b];
        if (h > 0) {
            const int gstart = (r * NBK + b) * CAPB + atomicAdd(&bcnt_s[r * NBK + b], h);
            gdelta[b] = gstart - lbase[b];
        }
    }
    __syncthreads();
    for (int i = tid; i < n; i += 256) {
        const int s = sp[i];
        const int b = s >> 7;
        const int pos = atomicAdd(&lcur[b], 1);
        staging16[pos] = (unsigned short)((b << 7) | (s & 127));
    }
    __syncthreads();
    for (int j = tid; j < n; j += 256) {
        const unsigned short v = staging16[j];
        const int b = v >> 7;
        const int gi = gdelta[b] + j;
        const int lo = gi - (r * NBK + b) * CAPB;
        if (lo < CAPB) pairs_s[gi] = v;
    }
}

// ---------------- per-bucket: sort edges by src>>6 (sweep locality) + degrees ----------------
__global__ __launch_bounds__(256) void sort_count_kernel(
    int* __restrict__ pairs_d, const unsigned short* __restrict__ pairs_s,
    const int* __restrict__ bcnt_d, const int* __restrict__ bcnt_s,
    float* __restrict__ degi_r, float* __restrict__ dego_r)
{
    __shared__ int stage[CAP];
    __shared__ int outb[CAP];
    __shared__ int cnt[BKT];
    __shared__ int scnt[BKT];
    __shared__ int h2[NSB];
    const int tid = threadIdx.x;
    const int bid = blockIdx.x;              // r*NBK + b
    const int n = min(bcnt_d[bid], CAP);
    const int n2 = min(bcnt_s[bid], CAPB);
    int* pp = pairs_d + (size_t)bid * CAP;
    const unsigned short* ps = pairs_s + (size_t)bid * CAPB;
    if (tid < BKT) { cnt[tid] = 0; scnt[tid] = 0; }
    for (int i = tid; i < NSB; i += 256) h2[i] = 0;
    __syncthreads();
    for (int i = tid; i < n; i += 256) {
        const int p = pp[i];
        stage[i] = p;
        atomicAdd(&cnt[p >> 16], 1);
        atomicAdd(&h2[(p & 0xFFFF) >> 6], 1);
    }
    for (int i = tid; i < n2; i += 256)
        atomicAdd(&scnt[ps[i] & 127], 1);
    __syncthreads();
    if (tid < 64) {                          // exclusive scan h2[0..NSB)
        int carry = 0;
        for (int c0 = 0; c0 < NSB; c0 += 64) {
            const int idx = c0 + tid;
            const int v = (idx < NSB) ? h2[idx] : 0;
            int incl = v;
            #pragma unroll
            for (int d = 1; d < 64; d <<= 1) {
                const int t = __shfl_up(incl, d, 64);
                if (tid >= d) incl += t;
            }
            if (idx < NSB) h2[idx] = carry + incl - v;
            carry += __shfl(incl, 63, 64);
        }
    }
    __syncthreads();
    for (int i = tid; i < n; i += 256) {     // scatter: sorted by src>>6
        const int p = stage[i];
        const int q = atomicAdd(&h2[(p & 0xFFFF) >> 6], 1);
        outb[q] = p;
    }
    __syncthreads();
    if (tid < BKT) {
        const int r = bid / NBK;
        const int g = (bid % NBK) * BKT + tid;
        if (g < NN) {
            degi_r[r * NN + g] = rsqrtf((float)max(cnt[tid], 1));
            dego_r[r * NN + g] = rsqrtf((float)max(scnt[tid], 1));
        }
    }
    for (int i = tid; i < n; i += 256)
        pp[i] = outb[i];
}

// ---------------- setup: x cast + W' prep (merged elementwise) ----------------
__global__ __launch_bounds__(256) void setup_kernel(
    const float* __restrict__ x, unsigned short* __restrict__ xb,
    const float* __restrict__ W1, const float* __restrict__ W2,
    const float* __restrict__ Wlin, unsigned short* __restrict__ Wt1,
    unsigned short* __restrict__ Wt2, unsigned short* __restrict__ WlT)
{
    const int i = blockIdx.x * 256 + threadIdx.x;   // 0 .. NN*DD/4-1 (1.6M)
    {   // cast x -> bf16 (full range)
        const float4 v = ((const float4*)x)[i];
        ushort4 o;
        o.x = f2b(v.x); o.y = f2b(v.y); o.z = f2b(v.z); o.w = f2b(v.w);
        ((ushort4*)xb)[i] = o;
    }
    if (i < RR * DD * DD) {
        const int r = i >> 14, rem = i & 16383, nn = rem >> 7, k = rem & 127;
        const float diag = (k == nn) ? 1.0f : 0.0f;
        const float w1 = W1[r * DD * DD + k * DD + nn];
        Wt1[i] = f2b(BETA1_ * w1 + diag * (1.0f - BETA1_));
        const float w2 = W2[r * DD * DD + k * DD + nn];
        Wt2[i] = f2b((BETA2_ * w2 + diag * (1.0f - BETA2_)) * (1.0f / 3.0f));
    } else if (i < RR * DD * DD + OUTD * DD) {
        const int j = i - RR * DD * DD;
        const int nn = j >> 7, k = j & 127;
        WlT[j] = f2b(Wlin[k * OUTD + nn]);
    }
}

// ---------------- sweep pull: per-bucket LDS fp32 accumulate over src-sorted edges ----------------
// Block = (relation, dst-bucket). 16 groups x 16 lanes; edges consumed in src order so all
// resident blocks' gathers stay in a narrow moving window (L2-resident). ds_add_f32 accumulation.
__global__ __launch_bounds__(256) void pull_sweep_kernel(
    const unsigned short* __restrict__ hb,   // gather table [N,128] bf16
    const unsigned short* __restrict__ xb,   // residual [N,128] bf16
    const int* __restrict__ pairs_d, const int* __restrict__ bcnt_d,
    const float* __restrict__ dego_r, const float* __restrict__ degi_r,
    unsigned short* __restrict__ aggb)
{
    __shared__ float acc[BKT * 129];         // 66048 B (stride 129 -> bank rotate per row)
    const int bid = blockIdx.x;              // r*NBK + bucket
    const int r = bid / NBK;
    const int bucket = bid % NBK;
    const int tid = threadIdx.x;
    const int group = tid >> 4;              // 0..15
    const int lane = tid & 15;
    for (int i = tid; i < BKT * 129; i += 256) acc[i] = 0.f;
    __syncthreads();

    const int n = min(bcnt_d[bid], CAP);
    const int* pp = pairs_d + (size_t)bid * CAP;
    const float* dego = dego_r + (size_t)r * NN;
    const uint4* hb4 = (const uint4*)hb;

    int e = group;
    for (; e + 16 < n; e += 32) {            // unroll x2 for MLP
        const int p0 = pp[e], p1 = pp[e + 16];
        const int s0 = p0 & 0xFFFF, s1 = p1 & 0xFFFF;
        const float n0 = dego[s0], n1 = dego[s1];
        const uint4 q0 = hb4[(size_t)s0 * 16 + lane];
        const uint4 q1 = hb4[(size_t)s1 * 16 + lane];
        float* a0 = acc + (p0 >> 16) * 129 + lane * 8;
        float* a1 = acc + (p1 >> 16) * 129 + lane * 8;
        unsafeAtomicAdd(&a0[0], blo(q0.x) * n0);
        unsafeAtomicAdd(&a0[1], bhi(q0.x) * n0);
        unsafeAtomicAdd(&a0[2], blo(q0.y) * n0);
        unsafeAtomicAdd(&a0[3], bhi(q0.y) * n0);
        unsafeAtomicAdd(&a0[4], blo(q0.z) * n0);
        unsafeAtomicAdd(&a0[5], bhi(q0.z) * n0);
        unsafeAtomicAdd(&a0[6], blo(q0.w) * n0);
        unsafeAtomicAdd(&a0[7], bhi(q0.w) * n0);
        unsafeAtomicAdd(&a1[0], blo(q1.x) * n1);
        unsafeAtomicAdd(&a1[1], bhi(q1.x) * n1);
        unsafeAtomicAdd(&a1[2], blo(q1.y) * n1);
        unsafeAtomicAdd(&a1[3], bhi(q1.y) * n1);
        unsafeAtomicAdd(&a1[4], blo(q1.z) * n1);
        unsafeAtomicAdd(&a1[5], bhi(q1.z) * n1);
        unsafeAtomicAdd(&a1[6], blo(q1.w) * n1);
        unsafeAtomicAdd(&a1[7], bhi(q1.w) * n1);
    }
    if (e < n) {
        const int p0 = pp[e];
        const int s0 = p0 & 0xFFFF;
        const float n0 = dego[s0];
        const uint4 q0 = hb4[(size_t)s0 * 16 + lane];
        float* a0 = acc + (p0 >> 16) * 129 + lane * 8;
        unsafeAtomicAdd(&a0[0], blo(q0.x) * n0);
        unsafeAtomicAdd(&a0[1], bhi(q0.x) * n0);
        unsafeAtomicAdd(&a0[2], blo(q0.y) * n0);
        unsafeAtomicAdd(&a0[3], bhi(q0.y) * n0);
        unsafeAtomicAdd(&a0[4], blo(q0.z) * n0);
        unsafeAtomicAdd(&a0[5], bhi(q0.z) * n0);
        unsafeAtomicAdd(&a0[6], blo(q0.w) * n0);
        unsafeAtomicAdd(&a0[7], bhi(q0.w) * n0);
    }
    __syncthreads();

    // epilogue: rst = acc * degi_norm * (1-a) + a * x, pack bf16, coalesced write
    const int node0 = bucket * BKT;
    for (int i = tid; i < BKT * 16; i += 256) {
        const int row = i >> 4, c = i & 15;
        const int node = node0 + row;
        if (node < NN) {
            const float nd = degi_r[r * NN + node] * (1.0f - ALPHA_);
            const uint4 xq = ((const uint4*)xb)[(size_t)node * 16 + c];
            const float* ap = acc + row * 129 + c * 8;
            uint4 o;
            o.x = pack2(ap[0] * nd + ALPHA_ * blo(xq.x), ap[1] * nd + ALPHA_ * bhi(xq.x));
            o.y = pack2(ap[2] * nd + ALPHA_ * blo(xq.y), ap[3] * nd + ALPHA_ * bhi(xq.y));
            o.z = pack2(ap[4] * nd + ALPHA_ * blo(xq.z), ap[5] * nd + ALPHA_ * bhi(xq.z));
            o.w = pack2(ap[6] * nd + ALPHA_ * blo(xq.w), ap[7] * nd + ALPHA_ * bhi(xq.w));
            ((uint4*)aggb)[((size_t)r * NN + node) * 16 + c] = o;
        }
    }
}

// ---------------- MFMA conv: rst_r @ W'_r (+bias-init) [+leaky] summed over r ----------------
template<int LIN>
__global__ __launch_bounds__(256) void conv_mfma_kernel(
    const unsigned short* __restrict__ aggb,   // [R][N][128] bf16
    const unsigned short* __restrict__ WtG,    // [R][128][128] bf16, [n][k]
    const float* __restrict__ bias,            // [R,128]
    const unsigned short* __restrict__ WlT,    // [64][128] bf16 (LIN)
    const float* __restrict__ blin,            // [64] (LIN)
    unsigned short* __restrict__ houtb,        // h1b (LIN=0)
    float* __restrict__ outf)                  // out [N,64] (LIN=1)
{
    __shared__ unsigned short WtL[DD * 136];   // 34816 B, stride 136 bf16 (17 uint4)
    uint4* WtL4 = (uint4*)WtL;
    const int tid  = threadIdx.x;
    const int wave = tid >> 6;
    const int lane = tid & 63;
    const int l15  = lane & 15;
    const int q    = lane >> 4;                // 0..3
    const int blockRow = blockIdx.x * 64;
    const int row0 = blockRow + wave * 16;
    const int arow = min(row0 + l15, NN - 1);  // A-frag row (clamped; OOB rows not stored)

    f32x4 o[8];
    if (LIN) {
        #pragma unroll
        for (int ct = 0; ct < 8; ++ct) {
            const int col = ct * 16 + l15;
            const float bv = (bias[col] + bias[DD + col] + bias[2 * DD + col]) * (1.0f / 3.0f);
            o[ct] = (f32x4){bv, bv, bv, bv};
        }
    } else {
        #pragma unroll
        for (int ct = 0; ct < 8; ++ct) o[ct] = (f32x4){0.f, 0.f, 0.f, 0.f};
    }

    for (int r = 0; r < RR; ++r) {
        __syncthreads();
        const uint4* wg = (const uint4*)(WtG + (size_t)r * DD * DD);
        for (int i = tid; i < DD * 16; i += 256)
            WtL4[(i >> 4) * 17 + (i & 15)] = wg[i];
        __syncthreads();

        short8 a[4];
        const uint4* ap = (const uint4*)aggb + ((size_t)r * NN + arow) * 16 + q;
        #pragma unroll
        for (int ks = 0; ks < 4; ++ks)
            a[ks] = __builtin_bit_cast(short8, ap[ks * 4]);

        #pragma unroll
        for (int ct = 0; ct < 8; ++ct) {
            f32x4 acc;
            if (LIN) {
                acc = o[ct];
            } else {
                const float bv = bias[r * DD + ct * 16 + l15];
                acc = (f32x4){bv, bv, bv, bv};
            }
            const int nrow = ct * 16 + l15;
            #pragma unroll
            for (int ks = 0; ks < 4; ++ks) {
                const short8 b = __builtin_bit_cast(short8, WtL4[nrow * 17 + ks * 4 + q]);
                acc = __builtin_amdgcn_mfma_f32_16x16x32_bf16(a[ks], b, acc, 0, 0, 0);
            }
            if (LIN) {
                o[ct] = acc;
            } else {
                #pragma unroll
                for (int e = 0; e < 4; ++e) {
                    float v = acc[e];
                    v = v >= 0.f ? v : SLOPE_ * v;
                    o[ct][e] += v * (1.0f / 3.0f);
                }
            }
        }
    }

    __syncthreads();
    unsigned short* tile = WtL;                // rows 0..63, stride 136
    #pragma unroll
    for (int ct = 0; ct < 8; ++ct) {
        const int col = ct * 16 + l15;
        #pragma unroll
        for (int e = 0; e < 4; ++e) {
            const int lrow = wave * 16 + q * 4 + e;
            tile[lrow * 136 + col] = f2b(o[ct][e]);
        }
    }
    if (LIN) {
        uint4* wl4 = WtL4 + 64 * 17;
        const uint4* wg = (const uint4*)WlT;
        for (int i = tid; i < OUTD * 16; i += 256)
            wl4[(i >> 4) * 17 + (i & 15)] = wg[i];
    }
    __syncthreads();

    if (!LIN) {
        for (int i = tid; i < 64 * 16; i += 256) {
            const int lrow = i >> 4, c = i & 15;
            const int grow = blockRow + lrow;
            if (grow < NN)
                ((uint4*)houtb)[(size_t)grow * 16 + c] = WtL4[lrow * 17 + c];
        }
    } else {
        short8 a2[4];
        const int lrow = wave * 16 + l15;
        #pragma unroll
        for (int ks = 0; ks < 4; ++ks)
            a2[ks] = __builtin_bit_cast(short8, WtL4[lrow * 17 + ks * 4 + q]);
        #pragma unroll
        for (int ct = 0; ct < 4; ++ct) {
            const int col = ct * 16 + l15;
            const float bv = blin[col];
            f32x4 acc = (f32x4){bv, bv, bv, bv};
            #pragma unroll
            for (int ks = 0; ks < 4; ++ks) {
                const short8 b = __builtin_bit_cast(short8, WtL4[(64 + col) * 17 + ks * 4 + q]);
                acc = __builtin_amdgcn_mfma_f32_16x16x32_bf16(a2[ks], b, acc, 0, 0, 0);
            }
            #pragma unroll
            for (int e = 0; e < 4; ++e) {
                const int grow = row0 + q * 4 + e;
                if (grow < NN) outf[(size_t)grow * OUTD + col] = acc[e];
            }
        }
    }
}

extern "C" void kernel_launch(void* const* d_in, const int* in_sizes, int n_in,
                              void* d_out, int out_size, void* d_ws, size_t ws_size,
                              hipStream_t stream)
{
    const float* x    = (const float*)d_in[0];
    const int*   src  = (const int*)  d_in[1];
    const int*   dst  = (const int*)  d_in[2];
    const float* W1   = (const float*)d_in[3];
    const float* b1   = (const float*)d_in[4];
    const float* W2   = (const float*)d_in[5];
    const float* b2   = (const float*)d_in[6];
    const float* Wlin = (const float*)d_in[7];
    const float* blin = (const float*)d_in[8];
    float* out = (float*)d_out;

    // ws layout (4B units): bcnt_d[3*NBK] | bcnt_s[3*NBK] | dego_r[3N] | degi_r[3N] |
    //   pairs_d[3*NBK*CAP] | pairs_s(u16, 3*NBK*CAPB) | xb(bf16 N*D) | h1b(bf16 N*D) |
    //   aggb(bf16 3*N*D) | Wt1 | Wt2 | WlT                                ~= 84 MB
    int*   bcnt_d  = (int*)d_ws;
    int*   bcnt_s  = bcnt_d + RR * NBK;
    float* dego_r  = (float*)(bcnt_s + RR * NBK);
    float* degi_r  = dego_r + RR * NN;
    int*   pairs_d = (int*)(degi_r + RR * NN);
    unsigned short* pairs_s = (unsigned short*)(pairs_d + (size_t)RR * NBK * CAP);
    unsigned short* xb   = pairs_s + (size_t)RR * NBK * CAPB;
    unsigned short* h1b  = xb + (size_t)NN * DD;
    unsigned short* aggb = h1b + (size_t)NN * DD;
    unsigned short* Wt1  = aggb + (size_t)RR * NN * DD;
    unsigned short* Wt2  = Wt1 + RR * DD * DD;
    unsigned short* WlT  = Wt2 + RR * DD * DD;

    hipMemsetAsync(bcnt_d, 0, (size_t)2 * RR * NBK * sizeof(int), stream);

    const int gemm_blocks = (NN + 63) / 64;

    // ---- graph preprocessing (once; same graph both layers) ----
    bin_kernel<<<RR * NCH, 256, 0, stream>>>(src, dst, bcnt_d, bcnt_s, pairs_d, pairs_s);
    setup_kernel<<<NN * DD / 4 / 256, 256, 0, stream>>>(
        x, xb, W1, W2, Wlin, Wt1, Wt2, WlT);
    sort_count_kernel<<<RR * NBK, 256, 0, stream>>>(
        pairs_d, pairs_s, bcnt_d, bcnt_s, degi_r, dego_r);

    // ---- conv1: h1b = bf16( mean_r leaky( rst_r @ W1'_r + b1_r ) ) ----
    pull_sweep_kernel<<<RR * NBK, 256, 0, stream>>>(
        xb, xb, pairs_d, bcnt_d, dego_r, degi_r, aggb);
    conv_mfma_kernel<0><<<gemm_blocks, 256, 0, stream>>>(
        aggb, Wt1, b1, nullptr, nullptr, h1b, nullptr);

    // ---- conv2 (+ fused final linear): out = ( sum_r rst_r @ (W2'_r/3) + mean b2 ) @ Wlin + blin ----
    pull_sweep_kernel<<<RR * NBK, 256, 0, stream>>>(
        h1b, xb, pairs_d, bcnt_d, dego_r, degi_r, aggb);
    conv_mfma_kernel<1><<<gemm_blocks, 256, 0, stream>>>(
        aggb, Wt2, b2, WlT, blin, nullptr, out);
}

// Round 10
// 526.314 us; speedup vs baseline: 6.7944x; 6.7944x over previous
//
#include <hip/hip_runtime.h>

#define NN    50000
#define DD    128
#define RR    3
#define EE    800000
#define OUTD  64
#define BKT   128                 // nodes per bucket (dst and src binning)
#define NBK   391                 // ceil(NN/BKT)
#define CAP   2560                // per-bucket edge capacity, 4B dst-entries
#define CAPB  2560                // per-bucket edge capacity, 2B src-entries
#define CHUNK 2048                // edges per bin block
#define NCH   391                 // ceil(EE/CHUNK)
#define NCK   4                   // feature chunks (32 feats = 64B each)
#define NNB   782                 // ceil(NN/64) node-blocks per chunk
#define ALPHA_ 0.5f
#define SLOPE_ 0.01f
#define BETA1_ 0.6931471805599453f   // log(2)
#define BETA2_ 0.4054651081081644f   // log(1.5)

typedef __attribute__((ext_vector_type(8))) short short8;   // 8 bf16 = 4 VGPRs
typedef __attribute__((ext_vector_type(4))) float f32x4;

__device__ __forceinline__ unsigned short f2b(float f) {   // fp32 -> bf16 RNE
    unsigned int u = __builtin_bit_cast(unsigned int, f);
    u += 0x7FFFu + ((u >> 16) & 1u);
    return (unsigned short)(u >> 16);
}
__device__ __forceinline__ unsigned int pack2(float lo, float hi) {
    return (unsigned int)f2b(lo) | ((unsigned int)f2b(hi) << 16);
}
__device__ __forceinline__ float blo(unsigned int w) { return __builtin_bit_cast(float, w << 16); }
__device__ __forceinline__ float bhi(unsigned int w) { return __builtin_bit_cast(float, w & 0xFFFF0000u); }

// ---------------- binning: two LDS bucket-sort phases (by dst>>7, then by src>>7) ----------------
__global__ __launch_bounds__(256) void bin_kernel(
    const int* __restrict__ src, const int* __restrict__ dst,
    int* __restrict__ bcnt_d, int* __restrict__ bcnt_s,
    int* __restrict__ pairs_d, unsigned short* __restrict__ pairs_s)
{
    __shared__ int hist[NBK];
    __shared__ int lbase[NBK];
    __shared__ int gdelta[NBK];
    __shared__ int lcur[NBK];
    __shared__ unsigned int staging[CHUNK];
    unsigned short* staging16 = (unsigned short*)staging;
    const int tid = threadIdx.x;
    const int r = blockIdx.x / NCH;
    const int chunk = blockIdx.x % NCH;
    const int e0 = chunk * CHUNK;
    const int n = min(CHUNK, EE - e0);
    const int* sp = src + (size_t)r * EE + e0;
    const int* dp = dst + (size_t)r * EE + e0;

    // phase A: bin by dst>>7
    for (int i = tid; i < NBK; i += 256) hist[i] = 0;
    __syncthreads();
    for (int i = tid; i < n; i += 256)
        atomicAdd(&hist[dp[i] >> 7], 1);
    __syncthreads();
    if (tid < 64) {
        int carry = 0;
        for (int c0 = 0; c0 < NBK; c0 += 64) {
            const int idx = c0 + tid;
            const int v = (idx < NBK) ? hist[idx] : 0;
            int incl = v;
            #pragma unroll
            for (int d = 1; d < 64; d <<= 1) {
                const int t = __shfl_up(incl, d, 64);
                if (tid >= d) incl += t;
            }
            if (idx < NBK) lbase[idx] = carry + incl - v;
            carry += __shfl(incl, 63, 64);
        }
    }
    __syncthreads();
    for (int b = tid; b < NBK; b += 256) {
        lcur[b] = lbase[b];
        const int h = hist[b];
        if (h > 0) {
            const int gstart = (r * NBK + b) * CAP + atomicAdd(&bcnt_d[r * NBK + b], h);
            gdelta[b] = gstart - lbase[b];
        }
    }
    __syncthreads();
    for (int i = tid; i < n; i += 256) {
        const int d = dp[i];
        const int b = d >> 7;
        const int pos = atomicAdd(&lcur[b], 1);
        staging[pos] = (unsigned int)sp[i] | ((unsigned int)(d & 127) << 16)
                     | ((unsigned int)b << 23);
    }
    __syncthreads();
    for (int j = tid; j < n; j += 256) {
        const unsigned int v = staging[j];
        const int b = v >> 23;
        const int gi = gdelta[b] + j;
        const int lo = gi - (r * NBK + b) * CAP;
        if (lo < CAP) pairs_d[gi] = (int)(v & 0x7FFFFF);
    }
    __syncthreads();

    // phase B: bin by src>>7 (for out-degree counting)
    for (int i = tid; i < NBK; i += 256) hist[i] = 0;
    __syncthreads();
    for (int i = tid; i < n; i += 256)
        atomicAdd(&hist[sp[i] >> 7], 1);
    __syncthreads();
    if (tid < 64) {
        int carry = 0;
        for (int c0 = 0; c0 < NBK; c0 += 64) {
            const int idx = c0 + tid;
            const int v = (idx < NBK) ? hist[idx] : 0;
            int incl = v;
            #pragma unroll
            for (int d = 1; d < 64; d <<= 1) {
                const int t = __shfl_up(incl, d, 64);
                if (tid >= d) incl += t;
            }
            if (idx < NBK) lbase[idx] = carry + incl - v;
            carry += __shfl(incl, 63, 64);
        }
    }
    __syncthreads();
    for (int b = tid; b < NBK; b += 256) {
        lcur[b] = lbase[b];
        const int h = hist[b];
        if (h > 0) {
            const int gstart = (r * NBK + b) * CAPB + atomicAdd(&bcnt_s[r * NBK + b], h);
            gdelta[b] = gstart - lbase[b];
        }
    }
    __syncthreads();
    for (int i = tid; i < n; i += 256) {
        const int s = sp[i];
        const int b = s >> 7;
        const int pos = atomicAdd(&lcur[b], 1);
        staging16[pos] = (unsigned short)((b << 7) | (s & 127));
    }
    __syncthreads();
    for (int j = tid; j < n; j += 256) {
        const unsigned short v = staging16[j];
        const int b = v >> 7;
        const int gi = gdelta[b] + j;
        const int lo = gi - (r * NBK + b) * CAPB;
        if (lo < CAPB) pairs_s[gi] = v;
    }
}

// ---------------- per-bucket: dlocal counting sort -> CSR + degi; src count -> dego ----------------
__global__ __launch_bounds__(256) void sort_count_kernel(
    int* __restrict__ pairs_d, const unsigned short* __restrict__ pairs_s,
    const int* __restrict__ bcnt_d, const int* __restrict__ bcnt_s,
    int* __restrict__ off_g, int* __restrict__ cnt_g,
    float* __restrict__ degi_r, float* __restrict__ dego_r)
{
    __shared__ int stage[CAP];
    __shared__ int cnt[BKT];
    __shared__ int base[BKT];
    __shared__ int pos[BKT];
    __shared__ int scnt[BKT];
    const int tid = threadIdx.x;
    const int bid = blockIdx.x;              // r*NBK + b
    const int n = min(bcnt_d[bid], CAP);
    const int n2 = min(bcnt_s[bid], CAPB);
    int* pp = pairs_d + (size_t)bid * CAP;
    const unsigned short* ps = pairs_s + (size_t)bid * CAPB;
    if (tid < BKT) { cnt[tid] = 0; scnt[tid] = 0; }
    __syncthreads();
    for (int i = tid; i < n; i += 256) {
        const int p = pp[i];
        stage[i] = p;
        atomicAdd(&cnt[p >> 16], 1);
    }
    for (int i = tid; i < n2; i += 256)
        atomicAdd(&scnt[ps[i] & 127], 1);
    __syncthreads();
    if (tid < 64) {
        int carry = 0;
        for (int c0 = 0; c0 < BKT; c0 += 64) {
            const int v = cnt[c0 + tid];
            int incl = v;
            #pragma unroll
            for (int d = 1; d < 64; d <<= 1) {
                const int t = __shfl_up(incl, d, 64);
                if (tid >= d) incl += t;
            }
            base[c0 + tid] = carry + incl - v;
            carry += __shfl(incl, 63, 64);
        }
    }
    __syncthreads();
    if (tid < BKT) {
        pos[tid] = base[tid];
        const int r = bid / NBK;
        const int g = (bid % NBK) * BKT + tid;
        if (g < NN) {
            off_g[r * NN + g] = bid * CAP + base[tid];
            cnt_g[r * NN + g] = cnt[tid];
            degi_r[r * NN + g] = rsqrtf((float)max(cnt[tid], 1));
            dego_r[r * NN + g] = rsqrtf((float)max(scnt[tid], 1));
        }
    }
    __syncthreads();
    for (int i = tid; i < n; i += 256) {
        const int p = stage[i];
        const int q = atomicAdd(&pos[p >> 16], 1);
        pp[q] = p & 0xFFFF;                  // src index only
    }
}

// ---------------- setup: x cast to CHUNK-MAJOR bf16 + W' prep ----------------
// xbc layout: [NCK][NN][32 feats] bf16 (each chunk slice = 3.2 MB, L2-resident)
__global__ __launch_bounds__(256) void setup_kernel(
    const float* __restrict__ x, unsigned short* __restrict__ xbc,
    const float* __restrict__ W1, const float* __restrict__ W2,
    const float* __restrict__ Wlin, unsigned short* __restrict__ Wt1,
    unsigned short* __restrict__ Wt2, unsigned short* __restrict__ WlT)
{
    const int i = blockIdx.x * 256 + threadIdx.x;   // 0 .. NN*DD/4-1 (1.6M)
    {
        const int node = i >> 5, j = i & 31;        // j: float4 index within row
        const int c = j >> 3, jj = j & 7;           // chunk, float4-within-chunk
        const float4 v = ((const float4*)x)[i];
        ushort4 o;
        o.x = f2b(v.x); o.y = f2b(v.y); o.z = f2b(v.z); o.w = f2b(v.w);
        ((ushort4*)xbc)[((size_t)c * NN + node) * 8 + jj] = o;
    }
    if (i < RR * DD * DD) {
        const int r = i >> 14, rem = i & 16383, nn = rem >> 7, k = rem & 127;
        const float diag = (k == nn) ? 1.0f : 0.0f;
        const float w1 = W1[r * DD * DD + k * DD + nn];
        Wt1[i] = f2b(BETA1_ * w1 + diag * (1.0f - BETA1_));
        const float w2 = W2[r * DD * DD + k * DD + nn];
        Wt2[i] = f2b((BETA2_ * w2 + diag * (1.0f - BETA2_)) * (1.0f / 3.0f));
    } else if (i < RR * DD * DD + OUTD * DD) {
        const int j = i - RR * DD * DD;
        const int nn = j >> 7, k = j & 127;
        WlT[j] = f2b(Wlin[k * OUTD + nn]);
    }
}

// ---------------- chunked pull: 4 lanes/node, register accumulate, chunk-major grid ----------------
// grid = NCK * NNB (chunk-major order). 48KB dynamic-LDS pad caps occupancy at 3 blocks/CU so
// co-resident blocks stay within ~one 3.2MB chunk slice (L2-resident gather).
__global__ __launch_bounds__(256) void pull_chunk_kernel(
    const uint4* __restrict__ hbc,   // [NCK][NN][4] uint4 chunk-major gather table
    const uint4* __restrict__ xbc,   // residual, same layout
    const int* __restrict__ pairs, const int* __restrict__ off_g,
    const int* __restrict__ cnt_g, const float* __restrict__ dego_r,
    const float* __restrict__ degi_r, uint4* __restrict__ aggb4)  // [R][NN][16]
{
    extern __shared__ char occ_pad[];          // occupancy cap only (unused)
    const int blk = blockIdx.x;
    const int c = blk / NNB;
    const int nb = blk % NNB;
    const int group = threadIdx.x >> 2;        // 0..63 -> node
    const int lane = threadIdx.x & 3;          // 16B of the 64B chunk row
    const int node = nb * 64 + group;
    if (node >= NN) return;
    const uint4* table = hbc + (size_t)c * NN * 4 + lane;
    const uint4 xq = xbc[((size_t)c * NN + node) * 4 + lane];

    for (int r = 0; r < RR; ++r) {
        const int gi = r * NN + node;
        const int n = cnt_g[gi];
        const int* pp = pairs + off_g[gi];
        const float* dego = dego_r + (size_t)r * NN;
        float a0 = 0.f, a1 = 0.f, a2 = 0.f, a3 = 0.f, a4 = 0.f, a5 = 0.f, a6 = 0.f, a7 = 0.f;
        int e = 0;
        for (; e + 4 <= n; e += 4) {
            const int s0 = pp[e], s1 = pp[e + 1], s2 = pp[e + 2], s3 = pp[e + 3];
            const float n0 = dego[s0], n1 = dego[s1], n2 = dego[s2], n3 = dego[s3];
            const uint4 q0 = table[(size_t)s0 * 4];
            const uint4 q1 = table[(size_t)s1 * 4];
            const uint4 q2 = table[(size_t)s2 * 4];
            const uint4 q3 = table[(size_t)s3 * 4];
            a0 += blo(q0.x) * n0 + blo(q1.x) * n1 + blo(q2.x) * n2 + blo(q3.x) * n3;
            a1 += bhi(q0.x) * n0 + bhi(q1.x) * n1 + bhi(q2.x) * n2 + bhi(q3.x) * n3;
            a2 += blo(q0.y) * n0 + blo(q1.y) * n1 + blo(q2.y) * n2 + blo(q3.y) * n3;
            a3 += bhi(q0.y) * n0 + bhi(q1.y) * n1 + bhi(q2.y) * n2 + bhi(q3.y) * n3;
            a4 += blo(q0.z) * n0 + blo(q1.z) * n1 + blo(q2.z) * n2 + blo(q3.z) * n3;
            a5 += bhi(q0.z) * n0 + bhi(q1.z) * n1 + bhi(q2.z) * n2 + bhi(q3.z) * n3;
            a6 += blo(q0.w) * n0 + blo(q1.w) * n1 + blo(q2.w) * n2 + blo(q3.w) * n3;
            a7 += bhi(q0.w) * n0 + bhi(q1.w) * n1 + bhi(q2.w) * n2 + bhi(q3.w) * n3;
        }
        for (; e < n; ++e) {
            const int s0 = pp[e];
            const float n0 = dego[s0];
            const uint4 q0 = table[(size_t)s0 * 4];
            a0 += blo(q0.x) * n0; a1 += bhi(q0.x) * n0;
            a2 += blo(q0.y) * n0; a3 += bhi(q0.y) * n0;
            a4 += blo(q0.z) * n0; a5 += bhi(q0.z) * n0;
            a6 += blo(q0.w) * n0; a7 += bhi(q0.w) * n0;
        }
        const float nd = degi_r[gi] * (1.0f - ALPHA_);
        uint4 o;
        o.x = pack2(a0 * nd + ALPHA_ * blo(xq.x), a1 * nd + ALPHA_ * bhi(xq.x));
        o.y = pack2(a2 * nd + ALPHA_ * blo(xq.y), a3 * nd + ALPHA_ * bhi(xq.y));
        o.z = pack2(a4 * nd + ALPHA_ * blo(xq.z), a5 * nd + ALPHA_ * bhi(xq.z));
        o.w = pack2(a6 * nd + ALPHA_ * blo(xq.w), a7 * nd + ALPHA_ * bhi(xq.w));
        aggb4[(size_t)gi * 16 + c * 4 + lane] = o;
    }
}

// ---------------- MFMA conv: rst_r @ W'_r (+bias-init) [+leaky] summed over r ----------------
// LIN=0: write h1 CHUNK-MAJOR bf16. LIN=1: fused @Wlin, write out fp32.
template<int LIN>
__global__ __launch_bounds__(256) void conv_mfma_kernel(
    const unsigned short* __restrict__ aggb,   // [R][N][128] bf16 (dst-major)
    const unsigned short* __restrict__ WtG,    // [R][128][128] bf16, [n][k]
    const float* __restrict__ bias,            // [R,128]
    const unsigned short* __restrict__ WlT,    // [64][128] bf16 (LIN)
    const float* __restrict__ blin,            // [64] (LIN)
    uint4* __restrict__ h1bc4,                 // chunk-major h1 (LIN=0)
    float* __restrict__ outf)                  // out [N,64] (LIN=1)
{
    __shared__ unsigned short WtL[DD * 136];   // 34816 B, stride 136 bf16 (17 uint4)
    uint4* WtL4 = (uint4*)WtL;
    const int tid  = threadIdx.x;
    const int wave = tid >> 6;
    const int lane = tid & 63;
    const int l15  = lane & 15;
    const int q    = lane >> 4;                // 0..3
    const int blockRow = blockIdx.x * 64;
    const int row0 = blockRow + wave * 16;
    const int arow = min(row0 + l15, NN - 1);

    f32x4 o[8];
    if (LIN) {
        #pragma unroll
        for (int ct = 0; ct < 8; ++ct) {
            const int col = ct * 16 + l15;
            const float bv = (bias[col] + bias[DD + col] + bias[2 * DD + col]) * (1.0f / 3.0f);
            o[ct] = (f32x4){bv, bv, bv, bv};
        }
    } else {
        #pragma unroll
        for (int ct = 0; ct < 8; ++ct) o[ct] = (f32x4){0.f, 0.f, 0.f, 0.f};
    }

    for (int r = 0; r < RR; ++r) {
        __syncthreads();
        const uint4* wg = (const uint4*)(WtG + (size_t)r * DD * DD);
        for (int i = tid; i < DD * 16; i += 256)
            WtL4[(i >> 4) * 17 + (i & 15)] = wg[i];
        __syncthreads();

        short8 a[4];
        const uint4* ap = (const uint4*)aggb + ((size_t)r * NN + arow) * 16 + q;
        #pragma unroll
        for (int ks = 0; ks < 4; ++ks)
            a[ks] = __builtin_bit_cast(short8, ap[ks * 4]);

        #pragma unroll
        for (int ct = 0; ct < 8; ++ct) {
            f32x4 acc;
            if (LIN) {
                acc = o[ct];
            } else {
                const float bv = bias[r * DD + ct * 16 + l15];
                acc = (f32x4){bv, bv, bv, bv};
            }
            const int nrow = ct * 16 + l15;
            #pragma unroll
            for (int ks = 0; ks < 4; ++ks) {
                const short8 b = __builtin_bit_cast(short8, WtL4[nrow * 17 + ks * 4 + q]);
                acc = __builtin_amdgcn_mfma_f32_16x16x32_bf16(a[ks], b, acc, 0, 0, 0);
            }
            if (LIN) {
                o[ct] = acc;
            } else {
                #pragma unroll
                for (int e = 0; e < 4; ++e) {
                    float v = acc[e];
                    v = v >= 0.f ? v : SLOPE_ * v;
                    o[ct][e] += v * (1.0f / 3.0f);
                }
            }
        }
    }

    __syncthreads();
    unsigned short* tile = WtL;                // rows 0..63, stride 136
    #pragma unroll
    for (int ct = 0; ct < 8; ++ct) {
        const int col = ct * 16 + l15;
        #pragma unroll
        for (int e = 0; e < 4; ++e) {
            const int lrow = wave * 16 + q * 4 + e;
            tile[lrow * 136 + col] = f2b(o[ct][e]);
        }
    }
    if (LIN) {
        uint4* wl4 = WtL4 + 64 * 17;
        const uint4* wg = (const uint4*)WlT;
        for (int i = tid; i < OUTD * 16; i += 256)
            wl4[(i >> 4) * 17 + (i & 15)] = wg[i];
    }
    __syncthreads();

    if (!LIN) {
        // copy-out to chunk-major h1: uint4 cc covers feats 8cc..8cc+7 -> chunk cc>>2, slot cc&3
        for (int i = tid; i < 64 * 16; i += 256) {
            const int lrow = i >> 4, cc = i & 15;
            const int grow = blockRow + lrow;
            if (grow < NN)
                h1bc4[((size_t)(cc >> 2) * NN + grow) * 4 + (cc & 3)] = WtL4[lrow * 17 + cc];
        }
    } else {
        short8 a2[4];
        const int lrow = wave * 16 + l15;
        #pragma unroll
        for (int ks = 0; ks < 4; ++ks)
            a2[ks] = __builtin_bit_cast(short8, WtL4[lrow * 17 + ks * 4 + q]);
        #pragma unroll
        for (int ct = 0; ct < 4; ++ct) {
            const int col = ct * 16 + l15;
            const float bv = blin[col];
            f32x4 acc = (f32x4){bv, bv, bv, bv};
            #pragma unroll
            for (int ks = 0; ks < 4; ++ks) {
                const short8 b = __builtin_bit_cast(short8, WtL4[(64 + col) * 17 + ks * 4 + q]);
                acc = __builtin_amdgcn_mfma_f32_16x16x32_bf16(a2[ks], b, acc, 0, 0, 0);
            }
            #pragma unroll
            for (int e = 0; e < 4; ++e) {
                const int grow = row0 + q * 4 + e;
                if (grow < NN) outf[(size_t)grow * OUTD + col] = acc[e];
            }
        }
    }
}

extern "C" void kernel_launch(void* const* d_in, const int* in_sizes, int n_in,
                              void* d_out, int out_size, void* d_ws, size_t ws_size,
                              hipStream_t stream)
{
    const float* x    = (const float*)d_in[0];
    const int*   src  = (const int*)  d_in[1];
    const int*   dst  = (const int*)  d_in[2];
    const float* W1   = (const float*)d_in[3];
    const float* b1   = (const float*)d_in[4];
    const float* W2   = (const float*)d_in[5];
    const float* b2   = (const float*)d_in[6];
    const float* Wlin = (const float*)d_in[7];
    const float* blin = (const float*)d_in[8];
    float* out = (float*)d_out;

    // ws layout (4B units): bcnt_d[3*NBK] | bcnt_s[3*NBK] | dego_r[3N] | degi_r[3N] |
    //   off_g[3N] | cnt_g[3N] | pad[2] | pairs_d[3*NBK*CAP] | pairs_s(u16) |
    //   xbc(bf16 N*D chunk-major) | h1bc(bf16 N*D chunk-major) | aggb(bf16 3*N*D) |
    //   Wt1 | Wt2 | WlT                                                   ~= 85 MB
    int*   bcnt_d  = (int*)d_ws;
    int*   bcnt_s  = bcnt_d + RR * NBK;
    float* dego_r  = (float*)(bcnt_s + RR * NBK);
    float* degi_r  = dego_r + RR * NN;
    int*   off_g   = (int*)(degi_r + RR * NN);
    int*   cnt_g   = off_g + RR * NN;
    int*   pairs_d = cnt_g + RR * NN + 2;    // +2 -> 16B alignment downstream
    unsigned short* pairs_s = (unsigned short*)(pairs_d + (size_t)RR * NBK * CAP);
    unsigned short* xbc  = pairs_s + (size_t)RR * NBK * CAPB;
    unsigned short* h1bc = xbc + (size_t)NN * DD;
    unsigned short* aggb = h1bc + (size_t)NN * DD;
    unsigned short* Wt1  = aggb + (size_t)RR * NN * DD;
    unsigned short* Wt2  = Wt1 + RR * DD * DD;
    unsigned short* WlT  = Wt2 + RR * DD * DD;

    hipMemsetAsync(bcnt_d, 0, (size_t)2 * RR * NBK * sizeof(int), stream);

    const int gemm_blocks = (NN + 63) / 64;
    const int PAD_LDS = 49152;               // 48KB -> 3 blocks/CU occupancy cap

    // ---- graph preprocessing (once; same graph both layers) ----
    bin_kernel<<<RR * NCH, 256, 0, stream>>>(src, dst, bcnt_d, bcnt_s, pairs_d, pairs_s);
    setup_kernel<<<NN * DD / 4 / 256, 256, 0, stream>>>(
        x, xbc, W1, W2, Wlin, Wt1, Wt2, WlT);
    sort_count_kernel<<<RR * NBK, 256, 0, stream>>>(
        pairs_d, pairs_s, bcnt_d, bcnt_s, off_g, cnt_g, degi_r, dego_r);

    // ---- conv1: h1bc = bf16( mean_r leaky( rst_r @ W1'_r + b1_r ) ) ----
    pull_chunk_kernel<<<NCK * NNB, 256, PAD_LDS, stream>>>(
        (const uint4*)xbc, (const uint4*)xbc, pairs_d, off_g, cnt_g,
        dego_r, degi_r, (uint4*)aggb);
    conv_mfma_kernel<0><<<gemm_blocks, 256, 0, stream>>>(
        aggb, Wt1, b1, nullptr, nullptr, (uint4*)h1bc, nullptr);

    // ---- conv2 (+ fused final linear) ----
    pull_chunk_kernel<<<NCK * NNB, 256, PAD_LDS, stream>>>(
        (const uint4*)h1bc, (const uint4*)xbc, pairs_d, off_g, cnt_g,
        dego_r, degi_r, (uint4*)aggb);
    conv_mfma_kernel<1><<<gemm_blocks, 256, 0, stream>>>(
        aggb, Wt2, b2, WlT, blin, nullptr, out);
}

// Round 11
// 472.831 us; speedup vs baseline: 7.5629x; 1.1131x over previous
//
#include <hip/hip_runtime.h>

#define NN    50000
#define DD    128
#define RR    3
#define EE    800000
#define OUTD  64
#define BKT   128                 // nodes per bucket (dst and src binning)
#define NBK   391                 // ceil(NN/BKT)
#define CAP   2560                // per-bucket edge capacity, 4B dst-entries
#define CAPB  2560                // per-bucket edge capacity, 2B src-entries
#define CHUNK 2048                // edges per bin block
#define NCH   391                 // ceil(EE/CHUNK)
#define NCK   4                   // feature chunks (32 feats = 64B each)
#define NNB   782                 // ceil(NN/64) node-blocks per chunk
#define ALPHA_ 0.5f
#define SLOPE_ 0.01f
#define BETA1_ 0.6931471805599453f   // log(2)
#define BETA2_ 0.4054651081081644f   // log(1.5)

typedef __attribute__((ext_vector_type(8))) short short8;   // 8 bf16 = 4 VGPRs
typedef __attribute__((ext_vector_type(4))) float f32x4;

__device__ __forceinline__ unsigned short f2b(float f) {   // fp32 -> bf16 RNE
    unsigned int u = __builtin_bit_cast(unsigned int, f);
    u += 0x7FFFu + ((u >> 16) & 1u);
    return (unsigned short)(u >> 16);
}
__device__ __forceinline__ unsigned int pack2(float lo, float hi) {
    return (unsigned int)f2b(lo) | ((unsigned int)f2b(hi) << 16);
}
__device__ __forceinline__ float blo(unsigned int w) { return __builtin_bit_cast(float, w << 16); }
__device__ __forceinline__ float bhi(unsigned int w) { return __builtin_bit_cast(float, w & 0xFFFF0000u); }

// ---------------- binning: two LDS bucket-sort phases (by dst>>7, then by src>>7) ----------------
__global__ __launch_bounds__(256) void bin_kernel(
    const int* __restrict__ src, const int* __restrict__ dst,
    int* __restrict__ bcnt_d, int* __restrict__ bcnt_s,
    int* __restrict__ pairs_d, unsigned short* __restrict__ pairs_s)
{
    __shared__ int hist[NBK];
    __shared__ int lbase[NBK];
    __shared__ int gdelta[NBK];
    __shared__ int lcur[NBK];
    __shared__ unsigned int staging[CHUNK];
    unsigned short* staging16 = (unsigned short*)staging;
    const int tid = threadIdx.x;
    const int r = blockIdx.x / NCH;
    const int chunk = blockIdx.x % NCH;
    const int e0 = chunk * CHUNK;
    const int n = min(CHUNK, EE - e0);
    const int* sp = src + (size_t)r * EE + e0;
    const int* dp = dst + (size_t)r * EE + e0;

    // phase A: bin by dst>>7
    for (int i = tid; i < NBK; i += 256) hist[i] = 0;
    __syncthreads();
    for (int i = tid; i < n; i += 256)
        atomicAdd(&hist[dp[i] >> 7], 1);
    __syncthreads();
    if (tid < 64) {
        int carry = 0;
        for (int c0 = 0; c0 < NBK; c0 += 64) {
            const int idx = c0 + tid;
            const int v = (idx < NBK) ? hist[idx] : 0;
            int incl = v;
            #pragma unroll
            for (int d = 1; d < 64; d <<= 1) {
                const int t = __shfl_up(incl, d, 64);
                if (tid >= d) incl += t;
            }
            if (idx < NBK) lbase[idx] = carry + incl - v;
            carry += __shfl(incl, 63, 64);
        }
    }
    __syncthreads();
    for (int b = tid; b < NBK; b += 256) {
        lcur[b] = lbase[b];
        const int h = hist[b];
        if (h > 0) {
            const int gstart = (r * NBK + b) * CAP + atomicAdd(&bcnt_d[r * NBK + b], h);
            gdelta[b] = gstart - lbase[b];
        }
    }
    __syncthreads();
    for (int i = tid; i < n; i += 256) {
        const int d = dp[i];
        const int b = d >> 7;
        const int pos = atomicAdd(&lcur[b], 1);
        staging[pos] = (unsigned int)sp[i] | ((unsigned int)(d & 127) << 16)
                     | ((unsigned int)b << 23);
    }
    __syncthreads();
    for (int j = tid; j < n; j += 256) {
        const unsigned int v = staging[j];
        const int b = v >> 23;
        const int gi = gdelta[b] + j;
        const int lo = gi - (r * NBK + b) * CAP;
        if (lo < CAP) pairs_d[gi] = (int)(v & 0x7FFFFF);
    }
    __syncthreads();

    // phase B: bin by src>>7 (for out-degree counting)
    for (int i = tid; i < NBK; i += 256) hist[i] = 0;
    __syncthreads();
    for (int i = tid; i < n; i += 256)
        atomicAdd(&hist[sp[i] >> 7], 1);
    __syncthreads();
    if (tid < 64) {
        int carry = 0;
        for (int c0 = 0; c0 < NBK; c0 += 64) {
            const int idx = c0 + tid;
            const int v = (idx < NBK) ? hist[idx] : 0;
            int incl = v;
            #pragma unroll
            for (int d = 1; d < 64; d <<= 1) {
                const int t = __shfl_up(incl, d, 64);
                if (tid >= d) incl += t;
            }
            if (idx < NBK) lbase[idx] = carry + incl - v;
            carry += __shfl(incl, 63, 64);
        }
    }
    __syncthreads();
    for (int b = tid; b < NBK; b += 256) {
        lcur[b] = lbase[b];
        const int h = hist[b];
        if (h > 0) {
            const int gstart = (r * NBK + b) * CAPB + atomicAdd(&bcnt_s[r * NBK + b], h);
            gdelta[b] = gstart - lbase[b];
        }
    }
    __syncthreads();
    for (int i = tid; i < n; i += 256) {
        const int s = sp[i];
        const int b = s >> 7;
        const int pos = atomicAdd(&lcur[b], 1);
        staging16[pos] = (unsigned short)((b << 7) | (s & 127));
    }
    __syncthreads();
    for (int j = tid; j < n; j += 256) {
        const unsigned short v = staging16[j];
        const int b = v >> 7;
        const int gi = gdelta[b] + j;
        const int lo = gi - (r * NBK + b) * CAPB;
        if (lo < CAPB) pairs_s[gi] = v;
    }
}

// ---------------- per-bucket: dlocal counting sort -> u16 CSR + degi; src count -> dego ----------------
__global__ __launch_bounds__(256) void sort_count_kernel(
    const int* __restrict__ pairs_d, const unsigned short* __restrict__ pairs_s,
    const int* __restrict__ bcnt_d, const int* __restrict__ bcnt_s,
    unsigned short* __restrict__ csr16,
    int* __restrict__ off_g, int* __restrict__ cnt_g,
    float* __restrict__ degi_r, float* __restrict__ dego_r)
{
    __shared__ int stage[CAP];
    __shared__ int cnt[BKT];
    __shared__ int base[BKT];
    __shared__ int pos[BKT];
    __shared__ int scnt[BKT];
    const int tid = threadIdx.x;
    const int bid = blockIdx.x;              // r*NBK + b
    const int n = min(bcnt_d[bid], CAP);
    const int n2 = min(bcnt_s[bid], CAPB);
    const int* pp = pairs_d + (size_t)bid * CAP;
    const unsigned short* ps = pairs_s + (size_t)bid * CAPB;
    unsigned short* co = csr16 + (size_t)bid * CAP;
    if (tid < BKT) { cnt[tid] = 0; scnt[tid] = 0; }
    __syncthreads();
    for (int i = tid; i < n; i += 256) {
        const int p = pp[i];
        stage[i] = p;
        atomicAdd(&cnt[p >> 16], 1);
    }
    for (int i = tid; i < n2; i += 256)
        atomicAdd(&scnt[ps[i] & 127], 1);
    __syncthreads();
    if (tid < 64) {
        int carry = 0;
        for (int c0 = 0; c0 < BKT; c0 += 64) {
            const int v = cnt[c0 + tid];
            int incl = v;
            #pragma unroll
            for (int d = 1; d < 64; d <<= 1) {
                const int t = __shfl_up(incl, d, 64);
                if (tid >= d) incl += t;
            }
            base[c0 + tid] = carry + incl - v;
            carry += __shfl(incl, 63, 64);
        }
    }
    __syncthreads();
    if (tid < BKT) {
        pos[tid] = base[tid];
        const int r = bid / NBK;
        const int g = (bid % NBK) * BKT + tid;
        if (g < NN) {
            off_g[r * NN + g] = bid * CAP + base[tid];
            cnt_g[r * NN + g] = cnt[tid];
            degi_r[r * NN + g] = rsqrtf((float)max(cnt[tid], 1));
            dego_r[r * NN + g] = rsqrtf((float)max(scnt[tid], 1));
        }
    }
    __syncthreads();
    for (int i = tid; i < n; i += 256) {
        const int p = stage[i];
        const int q = atomicAdd(&pos[p >> 16], 1);
        co[q] = (unsigned short)(p & 0xFFFF);   // src index (fits 16 bits)
    }
}

// ---------------- setup: x cast to CHUNK-MAJOR bf16 + W' prep ----------------
// xbc layout: [NCK][NN][32 feats] bf16 (each chunk slice = 3.2 MB, fits one XCD L2)
__global__ __launch_bounds__(256) void setup_kernel(
    const float* __restrict__ x, unsigned short* __restrict__ xbc,
    const float* __restrict__ W1, const float* __restrict__ W2,
    const float* __restrict__ Wlin, unsigned short* __restrict__ Wt1,
    unsigned short* __restrict__ Wt2, unsigned short* __restrict__ WlT)
{
    const int i = blockIdx.x * 256 + threadIdx.x;   // 0 .. NN*DD/4-1 (1.6M)
    {
        const int node = i >> 5, j = i & 31;        // j: float4 index within row
        const int c = j >> 3, jj = j & 7;           // chunk, float4-within-chunk
        const float4 v = ((const float4*)x)[i];
        ushort4 o;
        o.x = f2b(v.x); o.y = f2b(v.y); o.z = f2b(v.z); o.w = f2b(v.w);
        ((ushort4*)xbc)[((size_t)c * NN + node) * 8 + jj] = o;
    }
    if (i < RR * DD * DD) {
        const int r = i >> 14, rem = i & 16383, nn = rem >> 7, k = rem & 127;
        const float diag = (k == nn) ? 1.0f : 0.0f;
        const float w1 = W1[r * DD * DD + k * DD + nn];
        Wt1[i] = f2b(BETA1_ * w1 + diag * (1.0f - BETA1_));
        const float w2 = W2[r * DD * DD + k * DD + nn];
        Wt2[i] = f2b((BETA2_ * w2 + diag * (1.0f - BETA2_)) * (1.0f / 3.0f));
    } else if (i < RR * DD * DD + OUTD * DD) {
        const int j = i - RR * DD * DD;
        const int nn = j >> 7, k = j & 127;
        WlT[j] = f2b(Wlin[k * OUTD + nn]);
    }
}

// ---------------- chunked pull, XCD-pinned: chunk = blockIdx % 4 ----------------
// Round-robin block->XCD dispatch means XCD k only ever touches chunk k%4's 3.2MB slice,
// keeping the gather L2-resident WITHOUT capping occupancy. 4 lanes/node, reg accumulate.
__global__ __launch_bounds__(256) void pull_chunk_kernel(
    const uint4* __restrict__ hbc,   // [NCK][NN][4] uint4 chunk-major gather table
    const uint4* __restrict__ xbc,   // residual, same layout
    const unsigned short* __restrict__ csr, const int* __restrict__ off_g,
    const int* __restrict__ cnt_g, const float* __restrict__ dego_r,
    const float* __restrict__ degi_r, uint4* __restrict__ aggb4)  // [R][NN][16]
{
    const int blk = blockIdx.x;
    const int c = blk % NCK;                   // XCD-pinned chunk
    const int nb = blk / NCK;
    const int group = threadIdx.x >> 2;        // 0..63 -> node
    const int lane = threadIdx.x & 3;          // 16B of the 64B chunk row
    const int node = nb * 64 + group;
    if (node >= NN) return;
    const uint4* table = hbc + (size_t)c * NN * 4 + lane;
    const uint4 xq = xbc[((size_t)c * NN + node) * 4 + lane];

    for (int r = 0; r < RR; ++r) {
        const int gi = r * NN + node;
        const int n = cnt_g[gi];
        const unsigned short* pp = csr + off_g[gi];
        const float* dego = dego_r + (size_t)r * NN;
        float a0 = 0.f, a1 = 0.f, a2 = 0.f, a3 = 0.f, a4 = 0.f, a5 = 0.f, a6 = 0.f, a7 = 0.f;
        int e = 0;
        for (; e + 4 <= n; e += 4) {
            const int s0 = pp[e], s1 = pp[e + 1], s2 = pp[e + 2], s3 = pp[e + 3];
            const float n0 = dego[s0], n1 = dego[s1], n2 = dego[s2], n3 = dego[s3];
            const uint4 q0 = table[(size_t)s0 * 4];
            const uint4 q1 = table[(size_t)s1 * 4];
            const uint4 q2 = table[(size_t)s2 * 4];
            const uint4 q3 = table[(size_t)s3 * 4];
            a0 += blo(q0.x) * n0 + blo(q1.x) * n1 + blo(q2.x) * n2 + blo(q3.x) * n3;
            a1 += bhi(q0.x) * n0 + bhi(q1.x) * n1 + bhi(q2.x) * n2 + bhi(q3.x) * n3;
            a2 += blo(q0.y) * n0 + blo(q1.y) * n1 + blo(q2.y) * n2 + blo(q3.y) * n3;
            a3 += bhi(q0.y) * n0 + bhi(q1.y) * n1 + bhi(q2.y) * n2 + bhi(q3.y) * n3;
            a4 += blo(q0.z) * n0 + blo(q1.z) * n1 + blo(q2.z) * n2 + blo(q3.z) * n3;
            a5 += bhi(q0.z) * n0 + bhi(q1.z) * n1 + bhi(q2.z) * n2 + bhi(q3.z) * n3;
            a6 += blo(q0.w) * n0 + blo(q1.w) * n1 + blo(q2.w) * n2 + blo(q3.w) * n3;
            a7 += bhi(q0.w) * n0 + bhi(q1.w) * n1 + bhi(q2.w) * n2 + bhi(q3.w) * n3;
        }
        for (; e < n; ++e) {
            const int s0 = pp[e];
            const float n0 = dego[s0];
            const uint4 q0 = table[(size_t)s0 * 4];
            a0 += blo(q0.x) * n0; a1 += bhi(q0.x) * n0;
            a2 += blo(q0.y) * n0; a3 += bhi(q0.y) * n0;
            a4 += blo(q0.z) * n0; a5 += bhi(q0.z) * n0;
            a6 += blo(q0.w) * n0; a7 += bhi(q0.w) * n0;
        }
        const float nd = degi_r[gi] * (1.0f - ALPHA_);
        uint4 o;
        o.x = pack2(a0 * nd + ALPHA_ * blo(xq.x), a1 * nd + ALPHA_ * bhi(xq.x));
        o.y = pack2(a2 * nd + ALPHA_ * blo(xq.y), a3 * nd + ALPHA_ * bhi(xq.y));
        o.z = pack2(a4 * nd + ALPHA_ * blo(xq.z), a5 * nd + ALPHA_ * bhi(xq.z));
        o.w = pack2(a6 * nd + ALPHA_ * blo(xq.w), a7 * nd + ALPHA_ * bhi(xq.w));
        aggb4[(size_t)gi * 16 + c * 4 + lane] = o;
    }
}

// ---------------- MFMA conv: rst_r @ W'_r (+bias-init) [+leaky] summed over r ----------------
// LIN=0: write h1 CHUNK-MAJOR bf16. LIN=1: fused @Wlin, write out fp32.
template<int LIN>
__global__ __launch_bounds__(256) void conv_mfma_kernel(
    const unsigned short* __restrict__ aggb,   // [R][N][128] bf16 (dst-major)
    const unsigned short* __restrict__ WtG,    // [R][128][128] bf16, [n][k]
    const float* __restrict__ bias,            // [R,128]
    const unsigned short* __restrict__ WlT,    // [64][128] bf16 (LIN)
    const float* __restrict__ blin,            // [64] (LIN)
    uint4* __restrict__ h1bc4,                 // chunk-major h1 (LIN=0)
    float* __restrict__ outf)                  // out [N,64] (LIN=1)
{
    __shared__ unsigned short WtL[DD * 136];   // 34816 B, stride 136 bf16 (17 uint4)
    uint4* WtL4 = (uint4*)WtL;
    const int tid  = threadIdx.x;
    const int wave = tid >> 6;
    const int lane = tid & 63;
    const int l15  = lane & 15;
    const int q    = lane >> 4;                // 0..3
    const int blockRow = blockIdx.x * 64;
    const int row0 = blockRow + wave * 16;
    const int arow = min(row0 + l15, NN - 1);

    f32x4 o[8];
    if (LIN) {
        #pragma unroll
        for (int ct = 0; ct < 8; ++ct) {
            const int col = ct * 16 + l15;
            const float bv = (bias[col] + bias[DD + col] + bias[2 * DD + col]) * (1.0f / 3.0f);
            o[ct] = (f32x4){bv, bv, bv, bv};
        }
    } else {
        #pragma unroll
        for (int ct = 0; ct < 8; ++ct) o[ct] = (f32x4){0.f, 0.f, 0.f, 0.f};
    }

    for (int r = 0; r < RR; ++r) {
        __syncthreads();
        const uint4* wg = (const uint4*)(WtG + (size_t)r * DD * DD);
        for (int i = tid; i < DD * 16; i += 256)
            WtL4[(i >> 4) * 17 + (i & 15)] = wg[i];
        __syncthreads();

        short8 a[4];
        const uint4* ap = (const uint4*)aggb + ((size_t)r * NN + arow) * 16 + q;
        #pragma unroll
        for (int ks = 0; ks < 4; ++ks)
            a[ks] = __builtin_bit_cast(short8, ap[ks * 4]);

        #pragma unroll
        for (int ct = 0; ct < 8; ++ct) {
            f32x4 acc;
            if (LIN) {
                acc = o[ct];
            } else {
                const float bv = bias[r * DD + ct * 16 + l15];
                acc = (f32x4){bv, bv, bv, bv};
            }
            const int nrow = ct * 16 + l15;
            #pragma unroll
            for (int ks = 0; ks < 4; ++ks) {
                const short8 b = __builtin_bit_cast(short8, WtL4[nrow * 17 + ks * 4 + q]);
                acc = __builtin_amdgcn_mfma_f32_16x16x32_bf16(a[ks], b, acc, 0, 0, 0);
            }
            if (LIN) {
                o[ct] = acc;
            } else {
                #pragma unroll
                for (int e = 0; e < 4; ++e) {
                    float v = acc[e];
                    v = v >= 0.f ? v : SLOPE_ * v;
                    o[ct][e] += v * (1.0f / 3.0f);
                }
            }
        }
    }

    __syncthreads();
    unsigned short* tile = WtL;                // rows 0..63, stride 136
    #pragma unroll
    for (int ct = 0; ct < 8; ++ct) {
        const int col = ct * 16 + l15;
        #pragma unroll
        for (int e = 0; e < 4; ++e) {
            const int lrow = wave * 16 + q * 4 + e;
            tile[lrow * 136 + col] = f2b(o[ct][e]);
        }
    }
    if (LIN) {
        uint4* wl4 = WtL4 + 64 * 17;
        const uint4* wg = (const uint4*)WlT;
        for (int i = tid; i < OUTD * 16; i += 256)
            wl4[(i >> 4) * 17 + (i & 15)] = wg[i];
    }
    __syncthreads();

    if (!LIN) {
        // copy-out to chunk-major h1: uint4 cc covers feats 8cc..8cc+7 -> chunk cc>>2, slot cc&3
        for (int i = tid; i < 64 * 16; i += 256) {
            const int lrow = i >> 4, cc = i & 15;
            const int grow = blockRow + lrow;
            if (grow < NN)
                h1bc4[((size_t)(cc >> 2) * NN + grow) * 4 + (cc & 3)] = WtL4[lrow * 17 + cc];
        }
    } else {
        short8 a2[4];
        const int lrow = wave * 16 + l15;
        #pragma unroll
        for (int ks = 0; ks < 4; ++ks)
            a2[ks] = __builtin_bit_cast(short8, WtL4[lrow * 17 + ks * 4 + q]);
        #pragma unroll
        for (int ct = 0; ct < 4; ++ct) {
            const int col = ct * 16 + l15;
            const float bv = blin[col];
            f32x4 acc = (f32x4){bv, bv, bv, bv};
            #pragma unroll
            for (int ks = 0; ks < 4; ++ks) {
                const short8 b = __builtin_bit_cast(short8, WtL4[(64 + col) * 17 + ks * 4 + q]);
                acc = __builtin_amdgcn_mfma_f32_16x16x32_bf16(a2[ks], b, acc, 0, 0, 0);
            }
            #pragma unroll
            for (int e = 0; e < 4; ++e) {
                const int grow = row0 + q * 4 + e;
                if (grow < NN) outf[(size_t)grow * OUTD + col] = acc[e];
            }
        }
    }
}

extern "C" void kernel_launch(void* const* d_in, const int* in_sizes, int n_in,
                              void* d_out, int out_size, void* d_ws, size_t ws_size,
                              hipStream_t stream)
{
    const float* x    = (const float*)d_in[0];
    const int*   src  = (const int*)  d_in[1];
    const int*   dst  = (const int*)  d_in[2];
    const float* W1   = (const float*)d_in[3];
    const float* b1   = (const float*)d_in[4];
    const float* W2   = (const float*)d_in[5];
    const float* b2   = (const float*)d_in[6];
    const float* Wlin = (const float*)d_in[7];
    const float* blin = (const float*)d_in[8];
    float* out = (float*)d_out;

    // ws layout (4B units): bcnt_d[3*NBK] | bcnt_s[3*NBK] | dego_r[3N] | degi_r[3N] |
    //   off_g[3N] | cnt_g[3N] | pad[2] | pairs_d[3*NBK*CAP] | pairs_s(u16) | csr16(u16) |
    //   xbc(bf16 chunk-major) | h1bc(bf16 chunk-major) | aggb(bf16 3*N*D) | Wt1|Wt2|WlT  ~= 91 MB
    int*   bcnt_d  = (int*)d_ws;
    int*   bcnt_s  = bcnt_d + RR * NBK;
    float* dego_r  = (float*)(bcnt_s + RR * NBK);
    float* degi_r  = dego_r + RR * NN;
    int*   off_g   = (int*)(degi_r + RR * NN);
    int*   cnt_g   = off_g + RR * NN;
    int*   pairs_d = cnt_g + RR * NN + 2;    // +2 -> 16B alignment downstream
    unsigned short* pairs_s = (unsigned short*)(pairs_d + (size_t)RR * NBK * CAP);
    unsigned short* csr16   = pairs_s + (size_t)RR * NBK * CAPB;
    unsigned short* xbc  = csr16 + (size_t)RR * NBK * CAP;
    unsigned short* h1bc = xbc + (size_t)NN * DD;
    unsigned short* aggb = h1bc + (size_t)NN * DD;
    unsigned short* Wt1  = aggb + (size_t)RR * NN * DD;
    unsigned short* Wt2  = Wt1 + RR * DD * DD;
    unsigned short* WlT  = Wt2 + RR * DD * DD;

    hipMemsetAsync(bcnt_d, 0, (size_t)2 * RR * NBK * sizeof(int), stream);

    const int gemm_blocks = (NN + 63) / 64;

    // ---- graph preprocessing (once; same graph both layers) ----
    bin_kernel<<<RR * NCH, 256, 0, stream>>>(src, dst, bcnt_d, bcnt_s, pairs_d, pairs_s);
    setup_kernel<<<NN * DD / 4 / 256, 256, 0, stream>>>(
        x, xbc, W1, W2, Wlin, Wt1, Wt2, WlT);
    sort_count_kernel<<<RR * NBK, 256, 0, stream>>>(
        pairs_d, pairs_s, bcnt_d, bcnt_s, csr16, off_g, cnt_g, degi_r, dego_r);

    // ---- conv1: h1bc = bf16( mean_r leaky( rst_r @ W1'_r + b1_r ) ) ----
    pull_chunk_kernel<<<NCK * NNB, 256, 0, stream>>>(
        (const uint4*)xbc, (const uint4*)xbc, csr16, off_g, cnt_g,
        dego_r, degi_r, (uint4*)aggb);
    conv_mfma_kernel<0><<<gemm_blocks, 256, 0, stream>>>(
        aggb, Wt1, b1, nullptr, nullptr, (uint4*)h1bc, nullptr);

    // ---- conv2 (+ fused final linear) ----
    pull_chunk_kernel<<<NCK * NNB, 256, 0, stream>>>(
        (const uint4*)h1bc, (const uint4*)xbc, csr16, off_g, cnt_g,
        dego_r, degi_r, (uint4*)aggb);
    conv_mfma_kernel<1><<<gemm_blocks, 256, 0, stream>>>(
        aggb, Wt2, b2, WlT, blin, nullptr, out);
}

// Round 12
// 418.225 us; speedup vs baseline: 8.5504x; 1.1306x over previous
//
#include <hip/hip_runtime.h>

#define NN    50000
#define DD    128
#define RR    3
#define EE    800000
#define OUTD  64
#define BKT   128                 // nodes per bucket (dst and src binning)
#define NBK   391                 // ceil(NN/BKT)
#define CAP   2560                // per-bucket edge capacity, 4B dst-entries
#define CAPB  2560                // per-bucket edge capacity, 2B src-entries
#define CHUNK 2048                // edges per bin block
#define NCH   391                 // ceil(EE/CHUNK)
#define NPB   3125                // NN/16 pull blocks per relation
#define ALPHA_ 0.5f
#define SLOPE_ 0.01f
#define BETA1_ 0.6931471805599453f   // log(2)
#define BETA2_ 0.4054651081081644f   // log(1.5)

typedef __attribute__((ext_vector_type(8))) short short8;   // 8 bf16 = 4 VGPRs
typedef __attribute__((ext_vector_type(4))) float f32x4;

__device__ __forceinline__ unsigned short f2b(float f) {   // fp32 -> bf16 RNE
    unsigned int u = __builtin_bit_cast(unsigned int, f);
    u += 0x7FFFu + ((u >> 16) & 1u);
    return (unsigned short)(u >> 16);
}
__device__ __forceinline__ unsigned int pack2(float lo, float hi) {
    return (unsigned int)f2b(lo) | ((unsigned int)f2b(hi) << 16);
}
__device__ __forceinline__ float blo(unsigned int w) { return __builtin_bit_cast(float, w << 16); }
__device__ __forceinline__ float bhi(unsigned int w) { return __builtin_bit_cast(float, w & 0xFFFF0000u); }

// ---------------- binning: two LDS bucket-sort phases (by dst>>7, then by src>>7) ----------------
// NO per-edge global atomics. Phase A payload: src(16)|dlocal(7)|bucket(9).
// Phase B payload (ushort): bucket(9)<<7 | slocal(7).
__global__ __launch_bounds__(256) void bin_kernel(
    const int* __restrict__ src, const int* __restrict__ dst,
    int* __restrict__ bcnt_d, int* __restrict__ bcnt_s,
    int* __restrict__ pairs_d, unsigned short* __restrict__ pairs_s)
{
    __shared__ int hist[NBK];
    __shared__ int lbase[NBK];
    __shared__ int gdelta[NBK];
    __shared__ int lcur[NBK];
    __shared__ unsigned int staging[CHUNK];
    unsigned short* staging16 = (unsigned short*)staging;
    const int tid = threadIdx.x;
    const int r = blockIdx.x / NCH;
    const int chunk = blockIdx.x % NCH;
    const int e0 = chunk * CHUNK;
    const int n = min(CHUNK, EE - e0);
    const int* sp = src + (size_t)r * EE + e0;
    const int* dp = dst + (size_t)r * EE + e0;

    // phase A: bin by dst>>7
    for (int i = tid; i < NBK; i += 256) hist[i] = 0;
    __syncthreads();
    for (int i = tid; i < n; i += 256)
        atomicAdd(&hist[dp[i] >> 7], 1);
    __syncthreads();
    if (tid < 64) {
        int carry = 0;
        for (int c0 = 0; c0 < NBK; c0 += 64) {
            const int idx = c0 + tid;
            const int v = (idx < NBK) ? hist[idx] : 0;
            int incl = v;
            #pragma unroll
            for (int d = 1; d < 64; d <<= 1) {
                const int t = __shfl_up(incl, d, 64);
                if (tid >= d) incl += t;
            }
            if (idx < NBK) lbase[idx] = carry + incl - v;
            carry += __shfl(incl, 63, 64);
        }
    }
    __syncthreads();
    for (int b = tid; b < NBK; b += 256) {
        lcur[b] = lbase[b];
        const int h = hist[b];
        if (h > 0) {
            const int gstart = (r * NBK + b) * CAP + atomicAdd(&bcnt_d[r * NBK + b], h);
            gdelta[b] = gstart - lbase[b];
        }
    }
    __syncthreads();
    for (int i = tid; i < n; i += 256) {
        const int d = dp[i];
        const int b = d >> 7;
        const int pos = atomicAdd(&lcur[b], 1);
        staging[pos] = (unsigned int)sp[i] | ((unsigned int)(d & 127) << 16)
                     | ((unsigned int)b << 23);
    }
    __syncthreads();
    for (int j = tid; j < n; j += 256) {
        const unsigned int v = staging[j];
        const int b = v >> 23;
        const int gi = gdelta[b] + j;
        const int lo = gi - (r * NBK + b) * CAP;
        if (lo < CAP) pairs_d[gi] = (int)(v & 0x7FFFFF);
    }
    __syncthreads();

    // phase B: bin by src>>7 (for out-degree counting)
    for (int i = tid; i < NBK; i += 256) hist[i] = 0;
    __syncthreads();
    for (int i = tid; i < n; i += 256)
        atomicAdd(&hist[sp[i] >> 7], 1);
    __syncthreads();
    if (tid < 64) {
        int carry = 0;
        for (int c0 = 0; c0 < NBK; c0 += 64) {
            const int idx = c0 + tid;
            const int v = (idx < NBK) ? hist[idx] : 0;
            int incl = v;
            #pragma unroll
            for (int d = 1; d < 64; d <<= 1) {
                const int t = __shfl_up(incl, d, 64);
                if (tid >= d) incl += t;
            }
            if (idx < NBK) lbase[idx] = carry + incl - v;
            carry += __shfl(incl, 63, 64);
        }
    }
    __syncthreads();
    for (int b = tid; b < NBK; b += 256) {
        lcur[b] = lbase[b];
        const int h = hist[b];
        if (h > 0) {
            const int gstart = (r * NBK + b) * CAPB + atomicAdd(&bcnt_s[r * NBK + b], h);
            gdelta[b] = gstart - lbase[b];
        }
    }
    __syncthreads();
    for (int i = tid; i < n; i += 256) {
        const int s = sp[i];
        const int b = s >> 7;
        const int pos = atomicAdd(&lcur[b], 1);
        staging16[pos] = (unsigned short)((b << 7) | (s & 127));
    }
    __syncthreads();
    for (int j = tid; j < n; j += 256) {
        const unsigned short v = staging16[j];
        const int b = v >> 7;
        const int gi = gdelta[b] + j;
        const int lo = gi - (r * NBK + b) * CAPB;
        if (lo < CAPB) pairs_s[gi] = v;
    }
}

// ---------------- out-degree per bucket from binned src entries -> dego_r ----------------
__global__ __launch_bounds__(256) void dego_kernel(
    const unsigned short* __restrict__ pairs_s, const int* __restrict__ bcnt_s,
    float* __restrict__ dego_r)
{
    __shared__ int scnt[BKT];
    const int tid = threadIdx.x;
    const int bid = blockIdx.x;              // r*NBK + b
    const int n2 = min(bcnt_s[bid], CAPB);
    const unsigned short* ps = pairs_s + (size_t)bid * CAPB;
    if (tid < BKT) scnt[tid] = 0;
    __syncthreads();
    for (int i = tid; i < n2; i += 256)
        atomicAdd(&scnt[ps[i] & 127], 1);
    __syncthreads();
    if (tid < BKT) {
        const int r = bid / NBK;
        const int g = (bid % NBK) * BKT + tid;
        if (g < NN)
            dego_r[r * NN + g] = rsqrtf((float)max(scnt[tid], 1));
    }
}

// ---------------- per-bucket counting sort (in place) -> weighted CSR + degi ----------------
// Output entry: src(16) | bf16(dego_r[src])<<16 — one coalesced read gives index AND weight.
__global__ __launch_bounds__(256) void sort_kernel(
    int* __restrict__ pairs_d, const int* __restrict__ bcnt_d,
    const float* __restrict__ dego_r,
    int* __restrict__ off_g, int* __restrict__ cnt_g, float* __restrict__ degi_r)
{
    __shared__ int stage[CAP];
    __shared__ int cnt[BKT];
    __shared__ int base[BKT];
    __shared__ int pos[BKT];
    const int tid = threadIdx.x;
    const int bid = blockIdx.x;              // r*NBK + b
    const int rr = bid / NBK;
    const int n = min(bcnt_d[bid], CAP);
    int* pp = pairs_d + (size_t)bid * CAP;
    const float* dego = dego_r + (size_t)rr * NN;
    if (tid < BKT) cnt[tid] = 0;
    __syncthreads();
    for (int i = tid; i < n; i += 256) {
        const int p = pp[i];
        stage[i] = p;
        atomicAdd(&cnt[p >> 16], 1);
    }
    __syncthreads();
    if (tid < 64) {
        int carry = 0;
        for (int c0 = 0; c0 < BKT; c0 += 64) {
            const int v = cnt[c0 + tid];
            int incl = v;
            #pragma unroll
            for (int d = 1; d < 64; d <<= 1) {
                const int t = __shfl_up(incl, d, 64);
                if (tid >= d) incl += t;
            }
            base[c0 + tid] = carry + incl - v;
            carry += __shfl(incl, 63, 64);
        }
    }
    __syncthreads();
    if (tid < BKT) {
        pos[tid] = base[tid];
        const int g = (bid % NBK) * BKT + tid;
        if (g < NN) {
            off_g[rr * NN + g] = bid * CAP + base[tid];
            cnt_g[rr * NN + g] = cnt[tid];
            degi_r[rr * NN + g] = rsqrtf((float)max(cnt[tid], 1));
        }
    }
    __syncthreads();
    for (int i = tid; i < n; i += 256) {
        const int p = stage[i];
        const int q = atomicAdd(&pos[p >> 16], 1);
        const int s = p & 0xFFFF;
        pp[q] = s | ((int)f2b(dego[s]) << 16);   // src + folded bf16 weight
    }
}

// ---------------- setup: x cast (row-major) + W' prep (merged elementwise) ----------------
__global__ __launch_bounds__(256) void setup_kernel(
    const float* __restrict__ x, unsigned short* __restrict__ xb,
    const float* __restrict__ W1, const float* __restrict__ W2,
    const float* __restrict__ Wlin, unsigned short* __restrict__ Wt1,
    unsigned short* __restrict__ Wt2, unsigned short* __restrict__ WlT)
{
    const int i = blockIdx.x * 256 + threadIdx.x;   // 0 .. NN*DD/4-1 (1.6M)
    {
        const float4 v = ((const float4*)x)[i];
        ushort4 o;
        o.x = f2b(v.x); o.y = f2b(v.y); o.z = f2b(v.z); o.w = f2b(v.w);
        ((ushort4*)xb)[i] = o;
    }
    if (i < RR * DD * DD) {
        const int r = i >> 14, rem = i & 16383, nn = rem >> 7, k = rem & 127;
        const float diag = (k == nn) ? 1.0f : 0.0f;
        const float w1 = W1[r * DD * DD + k * DD + nn];
        Wt1[i] = f2b(BETA1_ * w1 + diag * (1.0f - BETA1_));
        const float w2 = W2[r * DD * DD + k * DD + nn];
        Wt2[i] = f2b((BETA2_ * w2 + diag * (1.0f - BETA2_)) * (1.0f / 3.0f));
    } else if (i < RR * DD * DD + OUTD * DD) {
        const int j = i - RR * DD * DD;
        const int nn = j >> 7, k = j & 127;
        WlT[j] = f2b(Wlin[k * OUTD + nn]);
    }
}

// ---------------- merged pull (all 3 relations): weighted-CSR bf16 gather + residual ----------------
// 16 lanes per dst node, 16B/lane per edge, register accumulate, unroll-4.
// CSR entry carries src AND bf16 weight -> 2-level dependency chain (entry -> row).
__global__ __launch_bounds__(256) void pull_all_kernel(
    const unsigned short* __restrict__ hb,   // gather table [N,128] bf16
    const unsigned short* __restrict__ xb,   // residual [N,128] bf16
    const int* __restrict__ csrw, const int* __restrict__ off_g,
    const int* __restrict__ cnt_g, const float* __restrict__ degi_r,
    unsigned short* __restrict__ aggb)
{
    const int blk = blockIdx.x;              // r*NPB + nb
    const int r = blk / NPB;
    const int node = (blk % NPB) * 16 + (threadIdx.x >> 4);
    const int lane = threadIdx.x & 15;
    const int gi = r * NN + node;
    const int j0 = off_g[gi];
    const int j1 = j0 + cnt_g[gi];
    const uint4* hb4 = (const uint4*)hb;
    float a0 = 0.f, a1 = 0.f, a2 = 0.f, a3 = 0.f, a4 = 0.f, a5 = 0.f, a6 = 0.f, a7 = 0.f;
    int j = j0;
    for (; j + 4 <= j1; j += 4) {
        const unsigned int p0 = csrw[j],     p1 = csrw[j + 1];
        const unsigned int p2 = csrw[j + 2], p3 = csrw[j + 3];
        const float n0 = bhi(p0), n1 = bhi(p1), n2 = bhi(p2), n3 = bhi(p3);
        const uint4 q0 = hb4[(size_t)(p0 & 0xFFFF) * 16 + lane];
        const uint4 q1 = hb4[(size_t)(p1 & 0xFFFF) * 16 + lane];
        const uint4 q2 = hb4[(size_t)(p2 & 0xFFFF) * 16 + lane];
        const uint4 q3 = hb4[(size_t)(p3 & 0xFFFF) * 16 + lane];
        a0 += blo(q0.x) * n0 + blo(q1.x) * n1 + blo(q2.x) * n2 + blo(q3.x) * n3;
        a1 += bhi(q0.x) * n0 + bhi(q1.x) * n1 + bhi(q2.x) * n2 + bhi(q3.x) * n3;
        a2 += blo(q0.y) * n0 + blo(q1.y) * n1 + blo(q2.y) * n2 + blo(q3.y) * n3;
        a3 += bhi(q0.y) * n0 + bhi(q1.y) * n1 + bhi(q2.y) * n2 + bhi(q3.y) * n3;
        a4 += blo(q0.z) * n0 + blo(q1.z) * n1 + blo(q2.z) * n2 + blo(q3.z) * n3;
        a5 += bhi(q0.z) * n0 + bhi(q1.z) * n1 + bhi(q2.z) * n2 + bhi(q3.z) * n3;
        a6 += blo(q0.w) * n0 + blo(q1.w) * n1 + blo(q2.w) * n2 + blo(q3.w) * n3;
        a7 += bhi(q0.w) * n0 + bhi(q1.w) * n1 + bhi(q2.w) * n2 + bhi(q3.w) * n3;
    }
    for (; j < j1; ++j) {
        const unsigned int p0 = csrw[j];
        const float n0 = bhi(p0);
        const uint4 q0 = hb4[(size_t)(p0 & 0xFFFF) * 16 + lane];
        a0 += blo(q0.x) * n0; a1 += bhi(q0.x) * n0;
        a2 += blo(q0.y) * n0; a3 += bhi(q0.y) * n0;
        a4 += blo(q0.z) * n0; a5 += bhi(q0.z) * n0;
        a6 += blo(q0.w) * n0; a7 += bhi(q0.w) * n0;
    }
    const float nd = degi_r[gi] * (1.0f - ALPHA_);
    const uint4 xq = ((const uint4*)xb)[(size_t)node * 16 + lane];
    uint4 o;
    o.x = pack2(a0 * nd + ALPHA_ * blo(xq.x), a1 * nd + ALPHA_ * bhi(xq.x));
    o.y = pack2(a2 * nd + ALPHA_ * blo(xq.y), a3 * nd + ALPHA_ * bhi(xq.y));
    o.z = pack2(a4 * nd + ALPHA_ * blo(xq.z), a5 * nd + ALPHA_ * bhi(xq.z));
    o.w = pack2(a6 * nd + ALPHA_ * blo(xq.w), a7 * nd + ALPHA_ * bhi(xq.w));
    ((uint4*)aggb)[(size_t)gi * 16 + lane] = o;
}

// ---------------- MFMA conv: rst_r @ W'_r (+bias-init) [+leaky] summed over r ----------------
template<int LIN>
__global__ __launch_bounds__(256) void conv_mfma_kernel(
    const unsigned short* __restrict__ aggb,   // [R][N][128] bf16
    const unsigned short* __restrict__ WtG,    // [R][128][128] bf16, [n][k]
    const float* __restrict__ bias,            // [R,128]
    const unsigned short* __restrict__ WlT,    // [64][128] bf16 (LIN)
    const float* __restrict__ blin,            // [64] (LIN)
    unsigned short* __restrict__ houtb,        // h1b (LIN=0)
    float* __restrict__ outf)                  // out [N,64] (LIN=1)
{
    __shared__ unsigned short WtL[DD * 136];   // 34816 B, stride 136 bf16 (17 uint4)
    uint4* WtL4 = (uint4*)WtL;
    const int tid  = threadIdx.x;
    const int wave = tid >> 6;
    const int lane = tid & 63;
    const int l15  = lane & 15;
    const int q    = lane >> 4;                // 0..3
    const int blockRow = blockIdx.x * 64;
    const int row0 = blockRow + wave * 16;
    const int arow = min(row0 + l15, NN - 1);  // A-frag row (clamped)

    f32x4 o[8];
    if (LIN) {
        #pragma unroll
        for (int ct = 0; ct < 8; ++ct) {
            const int col = ct * 16 + l15;
            const float bv = (bias[col] + bias[DD + col] + bias[2 * DD + col]) * (1.0f / 3.0f);
            o[ct] = (f32x4){bv, bv, bv, bv};
        }
    } else {
        #pragma unroll
        for (int ct = 0; ct < 8; ++ct) o[ct] = (f32x4){0.f, 0.f, 0.f, 0.f};
    }

    for (int r = 0; r < RR; ++r) {
        __syncthreads();
        const uint4* wg = (const uint4*)(WtG + (size_t)r * DD * DD);
        for (int i = tid; i < DD * 16; i += 256)
            WtL4[(i >> 4) * 17 + (i & 15)] = wg[i];
        __syncthreads();

        short8 a[4];
        const uint4* ap = (const uint4*)aggb + ((size_t)r * NN + arow) * 16 + q;
        #pragma unroll
        for (int ks = 0; ks < 4; ++ks)
            a[ks] = __builtin_bit_cast(short8, ap[ks * 4]);

        #pragma unroll
        for (int ct = 0; ct < 8; ++ct) {
            f32x4 acc;
            if (LIN) {
                acc = o[ct];
            } else {
                const float bv = bias[r * DD + ct * 16 + l15];
                acc = (f32x4){bv, bv, bv, bv};
            }
            const int nrow = ct * 16 + l15;
            #pragma unroll
            for (int ks = 0; ks < 4; ++ks) {
                const short8 b = __builtin_bit_cast(short8, WtL4[nrow * 17 + ks * 4 + q]);
                acc = __builtin_amdgcn_mfma_f32_16x16x32_bf16(a[ks], b, acc, 0, 0, 0);
            }
            if (LIN) {
                o[ct] = acc;
            } else {
                #pragma unroll
                for (int e = 0; e < 4; ++e) {
                    float v = acc[e];
                    v = v >= 0.f ? v : SLOPE_ * v;
                    o[ct][e] += v * (1.0f / 3.0f);
                }
            }
        }
    }

    __syncthreads();
    unsigned short* tile = WtL;                // rows 0..63, stride 136
    #pragma unroll
    for (int ct = 0; ct < 8; ++ct) {
        const int col = ct * 16 + l15;
        #pragma unroll
        for (int e = 0; e < 4; ++e) {
            const int lrow = wave * 16 + q * 4 + e;
            tile[lrow * 136 + col] = f2b(o[ct][e]);
        }
    }
    if (LIN) {
        uint4* wl4 = WtL4 + 64 * 17;
        const uint4* wg = (const uint4*)WlT;
        for (int i = tid; i < OUTD * 16; i += 256)
            wl4[(i >> 4) * 17 + (i & 15)] = wg[i];
    }
    __syncthreads();

    if (!LIN) {
        for (int i = tid; i < 64 * 16; i += 256) {
            const int lrow = i >> 4, c = i & 15;
            const int grow = blockRow + lrow;
            if (grow < NN)
                ((uint4*)houtb)[(size_t)grow * 16 + c] = WtL4[lrow * 17 + c];
        }
    } else {
        short8 a2[4];
        const int lrow = wave * 16 + l15;
        #pragma unroll
        for (int ks = 0; ks < 4; ++ks)
            a2[ks] = __builtin_bit_cast(short8, WtL4[lrow * 17 + ks * 4 + q]);
        #pragma unroll
        for (int ct = 0; ct < 4; ++ct) {
            const int col = ct * 16 + l15;
            const float bv = blin[col];
            f32x4 acc = (f32x4){bv, bv, bv, bv};
            #pragma unroll
            for (int ks = 0; ks < 4; ++ks) {
                const short8 b = __builtin_bit_cast(short8, WtL4[(64 + col) * 17 + ks * 4 + q]);
                acc = __builtin_amdgcn_mfma_f32_16x16x32_bf16(a2[ks], b, acc, 0, 0, 0);
            }
            #pragma unroll
            for (int e = 0; e < 4; ++e) {
                const int grow = row0 + q * 4 + e;
                if (grow < NN) outf[(size_t)grow * OUTD + col] = acc[e];
            }
        }
    }
}

extern "C" void kernel_launch(void* const* d_in, const int* in_sizes, int n_in,
                              void* d_out, int out_size, void* d_ws, size_t ws_size,
                              hipStream_t stream)
{
    const float* x    = (const float*)d_in[0];
    const int*   src  = (const int*)  d_in[1];
    const int*   dst  = (const int*)  d_in[2];
    const float* W1   = (const float*)d_in[3];
    const float* b1   = (const float*)d_in[4];
    const float* W2   = (const float*)d_in[5];
    const float* b2   = (const float*)d_in[6];
    const float* Wlin = (const float*)d_in[7];
    const float* blin = (const float*)d_in[8];
    float* out = (float*)d_out;

    // ws layout (4B units): bcnt_d[3*NBK] | bcnt_s[3*NBK] | dego_r[3N] | degi_r[3N] |
    //   off_g[3N] | cnt_g[3N] | pad[2] | pairs_d[3*NBK*CAP] | pairs_s(u16) |
    //   xb(bf16 N*D) | h1b(bf16 N*D) | aggb(bf16 3*N*D) | Wt1 | Wt2 | WlT    ~= 85 MB
    int*   bcnt_d  = (int*)d_ws;
    int*   bcnt_s  = bcnt_d + RR * NBK;
    float* dego_r  = (float*)(bcnt_s + RR * NBK);
    float* degi_r  = dego_r + RR * NN;
    int*   off_g   = (int*)(degi_r + RR * NN);
    int*   cnt_g   = off_g + RR * NN;
    int*   pairs_d = cnt_g + RR * NN + 2;    // +2 -> 16B alignment downstream
    unsigned short* pairs_s = (unsigned short*)(pairs_d + (size_t)RR * NBK * CAP);
    unsigned short* xb   = pairs_s + (size_t)RR * NBK * CAPB;
    unsigned short* h1b  = xb + (size_t)NN * DD;
    unsigned short* aggb = h1b + (size_t)NN * DD;
    unsigned short* Wt1  = aggb + (size_t)RR * NN * DD;
    unsigned short* Wt2  = Wt1 + RR * DD * DD;
    unsigned short* WlT  = Wt2 + RR * DD * DD;

    hipMemsetAsync(bcnt_d, 0, (size_t)2 * RR * NBK * sizeof(int), stream);

    const int gemm_blocks = (NN + 63) / 64;

    // ---- graph preprocessing (once; same graph both layers) ----
    bin_kernel<<<RR * NCH, 256, 0, stream>>>(src, dst, bcnt_d, bcnt_s, pairs_d, pairs_s);
    dego_kernel<<<RR * NBK, 256, 0, stream>>>(pairs_s, bcnt_s, dego_r);
    setup_kernel<<<NN * DD / 4 / 256, 256, 0, stream>>>(
        x, xb, W1, W2, Wlin, Wt1, Wt2, WlT);
    sort_kernel<<<RR * NBK, 256, 0, stream>>>(
        pairs_d, bcnt_d, dego_r, off_g, cnt_g, degi_r);

    // ---- conv1: h1b = bf16( mean_r leaky( rst_r @ W1'_r + b1_r ) ) ----
    pull_all_kernel<<<RR * NPB, 256, 0, stream>>>(
        xb, xb, pairs_d, off_g, cnt_g, degi_r, aggb);
    conv_mfma_kernel<0><<<gemm_blocks, 256, 0, stream>>>(
        aggb, Wt1, b1, nullptr, nullptr, h1b, nullptr);

    // ---- conv2 (+ fused final linear): out = ( sum_r rst_r @ (W2'_r/3) + mean b2 ) @ Wlin + blin ----
    pull_all_kernel<<<RR * NPB, 256, 0, stream>>>(
        h1b, xb, pairs_d, off_g, cnt_g, degi_r, aggb);
    conv_mfma_kernel<1><<<gemm_blocks, 256, 0, stream>>>(
        aggb, Wt2, b2, WlT, blin, nullptr, out);
}

// Round 13
// 411.976 us; speedup vs baseline: 8.6800x; 1.0152x over previous
//
#include <hip/hip_runtime.h>

#define NN    50000
#define DD    128
#define RR    3
#define EE    800000
#define OUTD  64
#define BKT   128                 // nodes per bucket (dst and src binning)
#define NBK   391                 // ceil(NN/BKT)
#define CAP   2560                // per-bucket edge capacity, 4B dst-entries
#define CAPB  2560                // per-bucket edge capacity, 2B src-entries
#define CHUNK 2048                // edges per bin block
#define NCH   391                 // ceil(EE/CHUNK)
#define NPB   3125                // NN/16 pull blocks per relation
#define SETUPB 6250               // NN*DD/4/256 setup blocks
#define ALPHA_ 0.5f
#define SLOPE_ 0.01f
#define BETA1_ 0.6931471805599453f   // log(2)
#define BETA2_ 0.4054651081081644f   // log(1.5)

typedef __attribute__((ext_vector_type(8))) short short8;   // 8 bf16 = 4 VGPRs
typedef __attribute__((ext_vector_type(4))) float f32x4;

__device__ __forceinline__ unsigned short f2b(float f) {   // fp32 -> bf16 RNE
    unsigned int u = __builtin_bit_cast(unsigned int, f);
    u += 0x7FFFu + ((u >> 16) & 1u);
    return (unsigned short)(u >> 16);
}
__device__ __forceinline__ unsigned int pack2(float lo, float hi) {
    return (unsigned int)f2b(lo) | ((unsigned int)f2b(hi) << 16);
}
__device__ __forceinline__ float blo(unsigned int w) { return __builtin_bit_cast(float, w << 16); }
__device__ __forceinline__ float bhi(unsigned int w) { return __builtin_bit_cast(float, w & 0xFFFF0000u); }

// ---------------- binning: phase-split LDS bucket-sort (A: by dst>>7, B: by src>>7) ----------------
// Grid = 2*RR*NCH; low blocks run phase A, high blocks phase B — phases are independent,
// so splitting halves each block's serial hist->scan->reserve->scatter->copyout chain.
__global__ __launch_bounds__(256) void bin_kernel(
    const int* __restrict__ src, const int* __restrict__ dst,
    int* __restrict__ bcnt_d, int* __restrict__ bcnt_s,
    int* __restrict__ pairs_d, unsigned short* __restrict__ pairs_s)
{
    __shared__ int hist[NBK];
    __shared__ int lbase[NBK];
    __shared__ int gdelta[NBK];
    __shared__ int lcur[NBK];
    __shared__ unsigned int staging[CHUNK];
    unsigned short* staging16 = (unsigned short*)staging;
    const int tid = threadIdx.x;
    const int blk = blockIdx.x;
    const int phase = (blk >= RR * NCH);
    const int rb = phase ? blk - RR * NCH : blk;
    const int r = rb / NCH;
    const int chunk = rb % NCH;
    const int e0 = chunk * CHUNK;
    const int n = min(CHUNK, EE - e0);
    const int* sp = src + (size_t)r * EE + e0;
    const int* dp = dst + (size_t)r * EE + e0;
    const int* kp = phase ? sp : dp;         // key stream for this phase

    for (int i = tid; i < NBK; i += 256) hist[i] = 0;
    __syncthreads();
    for (int i = tid; i < n; i += 256)
        atomicAdd(&hist[kp[i] >> 7], 1);
    __syncthreads();
    if (tid < 64) {
        int carry = 0;
        for (int c0 = 0; c0 < NBK; c0 += 64) {
            const int idx = c0 + tid;
            const int v = (idx < NBK) ? hist[idx] : 0;
            int incl = v;
            #pragma unroll
            for (int d = 1; d < 64; d <<= 1) {
                const int t = __shfl_up(incl, d, 64);
                if (tid >= d) incl += t;
            }
            if (idx < NBK) lbase[idx] = carry + incl - v;
            carry += __shfl(incl, 63, 64);
        }
    }
    __syncthreads();
    if (!phase) {
        for (int b = tid; b < NBK; b += 256) {
            lcur[b] = lbase[b];
            const int h = hist[b];
            if (h > 0) {
                const int gstart = (r * NBK + b) * CAP + atomicAdd(&bcnt_d[r * NBK + b], h);
                gdelta[b] = gstart - lbase[b];
            }
        }
        __syncthreads();
        for (int i = tid; i < n; i += 256) {
            const int d = dp[i];
            const int b = d >> 7;
            const int pos = atomicAdd(&lcur[b], 1);
            staging[pos] = (unsigned int)sp[i] | ((unsigned int)(d & 127) << 16)
                         | ((unsigned int)b << 23);
        }
        __syncthreads();
        for (int j = tid; j < n; j += 256) {
            const unsigned int v = staging[j];
            const int b = v >> 23;
            const int gi = gdelta[b] + j;
            const int lo = gi - (r * NBK + b) * CAP;
            if (lo < CAP) pairs_d[gi] = (int)(v & 0x7FFFFF);
        }
    } else {
        for (int b = tid; b < NBK; b += 256) {
            lcur[b] = lbase[b];
            const int h = hist[b];
            if (h > 0) {
                const int gstart = (r * NBK + b) * CAPB + atomicAdd(&bcnt_s[r * NBK + b], h);
                gdelta[b] = gstart - lbase[b];
            }
        }
        __syncthreads();
        for (int i = tid; i < n; i += 256) {
            const int s = sp[i];
            const int b = s >> 7;
            const int pos = atomicAdd(&lcur[b], 1);
            staging16[pos] = (unsigned short)((b << 7) | (s & 127));
        }
        __syncthreads();
        for (int j = tid; j < n; j += 256) {
            const unsigned short v = staging16[j];
            const int b = v >> 7;
            const int gi = gdelta[b] + j;
            const int lo = gi - (r * NBK + b) * CAPB;
            if (lo < CAPB) pairs_s[gi] = v;
        }
    }
}

// ---------------- merged: dego count (low blocks) + x cast / W' prep (high blocks) ----------------
__global__ __launch_bounds__(256) void dego_setup_kernel(
    const unsigned short* __restrict__ pairs_s, const int* __restrict__ bcnt_s,
    float* __restrict__ dego_r,
    const float* __restrict__ x, unsigned short* __restrict__ xb,
    const float* __restrict__ W1, const float* __restrict__ W2,
    const float* __restrict__ Wlin, unsigned short* __restrict__ Wt1,
    unsigned short* __restrict__ Wt2, unsigned short* __restrict__ WlT)
{
    __shared__ int scnt[BKT];
    const int tid = threadIdx.x;
    const int blk = blockIdx.x;
    if (blk < RR * NBK) {
        // out-degree per bucket from binned src entries
        const int n2 = min(bcnt_s[blk], CAPB);
        const unsigned short* ps = pairs_s + (size_t)blk * CAPB;
        if (tid < BKT) scnt[tid] = 0;
        __syncthreads();
        for (int i = tid; i < n2; i += 256)
            atomicAdd(&scnt[ps[i] & 127], 1);
        __syncthreads();
        if (tid < BKT) {
            const int r = blk / NBK;
            const int g = (blk % NBK) * BKT + tid;
            if (g < NN)
                dego_r[r * NN + g] = rsqrtf((float)max(scnt[tid], 1));
        }
    } else {
        const int i = (blk - RR * NBK) * 256 + tid;   // 0 .. NN*DD/4-1
        {
            const float4 v = ((const float4*)x)[i];
            ushort4 o;
            o.x = f2b(v.x); o.y = f2b(v.y); o.z = f2b(v.z); o.w = f2b(v.w);
            ((ushort4*)xb)[i] = o;
        }
        if (i < RR * DD * DD) {
            const int r = i >> 14, rem = i & 16383, nn = rem >> 7, k = rem & 127;
            const float diag = (k == nn) ? 1.0f : 0.0f;
            const float w1 = W1[r * DD * DD + k * DD + nn];
            Wt1[i] = f2b(BETA1_ * w1 + diag * (1.0f - BETA1_));
            const float w2 = W2[r * DD * DD + k * DD + nn];
            Wt2[i] = f2b((BETA2_ * w2 + diag * (1.0f - BETA2_)) * (1.0f / 3.0f));
        } else if (i < RR * DD * DD + OUTD * DD) {
            const int j = i - RR * DD * DD;
            const int nn = j >> 7, k = j & 127;
            WlT[j] = f2b(Wlin[k * OUTD + nn]);
        }
    }
}

// ---------------- per-bucket counting sort (in place) -> weighted CSR + degi ----------------
// Output entry: src(16) | bf16(dego_r[src])<<16 — one coalesced read gives index AND weight.
__global__ __launch_bounds__(256) void sort_kernel(
    int* __restrict__ pairs_d, const int* __restrict__ bcnt_d,
    const float* __restrict__ dego_r,
    int* __restrict__ off_g, int* __restrict__ cnt_g, float* __restrict__ degi_r)
{
    __shared__ int stage[CAP];
    __shared__ int cnt[BKT];
    __shared__ int base[BKT];
    __shared__ int pos[BKT];
    const int tid = threadIdx.x;
    const int bid = blockIdx.x;              // r*NBK + b
    const int rr = bid / NBK;
    const int n = min(bcnt_d[bid], CAP);
    int* pp = pairs_d + (size_t)bid * CAP;
    const float* dego = dego_r + (size_t)rr * NN;
    if (tid < BKT) cnt[tid] = 0;
    __syncthreads();
    for (int i = tid; i < n; i += 256) {
        const int p = pp[i];
        stage[i] = p;
        atomicAdd(&cnt[p >> 16], 1);
    }
    __syncthreads();
    if (tid < 64) {
        int carry = 0;
        for (int c0 = 0; c0 < BKT; c0 += 64) {
            const int v = cnt[c0 + tid];
            int incl = v;
            #pragma unroll
            for (int d = 1; d < 64; d <<= 1) {
                const int t = __shfl_up(incl, d, 64);
                if (tid >= d) incl += t;
            }
            base[c0 + tid] = carry + incl - v;
            carry += __shfl(incl, 63, 64);
        }
    }
    __syncthreads();
    if (tid < BKT) {
        pos[tid] = base[tid];
        const int g = (bid % NBK) * BKT + tid;
        if (g < NN) {
            off_g[rr * NN + g] = bid * CAP + base[tid];
            cnt_g[rr * NN + g] = cnt[tid];
            degi_r[rr * NN + g] = rsqrtf((float)max(cnt[tid], 1));
        }
    }
    __syncthreads();
    for (int i = tid; i < n; i += 256) {
        const int p = stage[i];
        const int q = atomicAdd(&pos[p >> 16], 1);
        const int s = p & 0xFFFF;
        pp[q] = s | ((int)f2b(dego[s]) << 16);   // src + folded bf16 weight
    }
}

// ---------------- merged pull (all 3 relations): weighted-CSR bf16 gather + residual ----------------
// 16 lanes per dst node, 16B/lane per edge, register accumulate, unroll-4.
__global__ __launch_bounds__(256) void pull_all_kernel(
    const unsigned short* __restrict__ hb,   // gather table [N,128] bf16
    const unsigned short* __restrict__ xb,   // residual [N,128] bf16
    const int* __restrict__ csrw, const int* __restrict__ off_g,
    const int* __restrict__ cnt_g, const float* __restrict__ degi_r,
    unsigned short* __restrict__ aggb)
{
    const int blk = blockIdx.x;              // r*NPB + nb
    const int r = blk / NPB;
    const int node = (blk % NPB) * 16 + (threadIdx.x >> 4);
    const int lane = threadIdx.x & 15;
    const int gi = r * NN + node;
    const int j0 = off_g[gi];
    const int j1 = j0 + cnt_g[gi];
    const uint4* hb4 = (const uint4*)hb;
    float a0 = 0.f, a1 = 0.f, a2 = 0.f, a3 = 0.f, a4 = 0.f, a5 = 0.f, a6 = 0.f, a7 = 0.f;
    int j = j0;
    for (; j + 4 <= j1; j += 4) {
        const unsigned int p0 = csrw[j],     p1 = csrw[j + 1];
        const unsigned int p2 = csrw[j + 2], p3 = csrw[j + 3];
        const float n0 = bhi(p0), n1 = bhi(p1), n2 = bhi(p2), n3 = bhi(p3);
        const uint4 q0 = hb4[(size_t)(p0 & 0xFFFF) * 16 + lane];
        const uint4 q1 = hb4[(size_t)(p1 & 0xFFFF) * 16 + lane];
        const uint4 q2 = hb4[(size_t)(p2 & 0xFFFF) * 16 + lane];
        const uint4 q3 = hb4[(size_t)(p3 & 0xFFFF) * 16 + lane];
        a0 += blo(q0.x) * n0 + blo(q1.x) * n1 + blo(q2.x) * n2 + blo(q3.x) * n3;
        a1 += bhi(q0.x) * n0 + bhi(q1.x) * n1 + bhi(q2.x) * n2 + bhi(q3.x) * n3;
        a2 += blo(q0.y) * n0 + blo(q1.y) * n1 + blo(q2.y) * n2 + blo(q3.y) * n3;
        a3 += bhi(q0.y) * n0 + bhi(q1.y) * n1 + bhi(q2.y) * n2 + bhi(q3.y) * n3;
        a4 += blo(q0.z) * n0 + blo(q1.z) * n1 + blo(q2.z) * n2 + blo(q3.z) * n3;
        a5 += bhi(q0.z) * n0 + bhi(q1.z) * n1 + bhi(q2.z) * n2 + bhi(q3.z) * n3;
        a6 += blo(q0.w) * n0 + blo(q1.w) * n1 + blo(q2.w) * n2 + blo(q3.w) * n3;
        a7 += bhi(q0.w) * n0 + bhi(q1.w) * n1 + bhi(q2.w) * n2 + bhi(q3.w) * n3;
    }
    for (; j < j1; ++j) {
        const unsigned int p0 = csrw[j];
        const float n0 = bhi(p0);
        const uint4 q0 = hb4[(size_t)(p0 & 0xFFFF) * 16 + lane];
        a0 += blo(q0.x) * n0; a1 += bhi(q0.x) * n0;
        a2 += blo(q0.y) * n0; a3 += bhi(q0.y) * n0;
        a4 += blo(q0.z) * n0; a5 += bhi(q0.z) * n0;
        a6 += blo(q0.w) * n0; a7 += bhi(q0.w) * n0;
    }
    const float nd = degi_r[gi] * (1.0f - ALPHA_);
    const uint4 xq = ((const uint4*)xb)[(size_t)node * 16 + lane];
    uint4 o;
    o.x = pack2(a0 * nd + ALPHA_ * blo(xq.x), a1 * nd + ALPHA_ * bhi(xq.x));
    o.y = pack2(a2 * nd + ALPHA_ * blo(xq.y), a3 * nd + ALPHA_ * bhi(xq.y));
    o.z = pack2(a4 * nd + ALPHA_ * blo(xq.z), a5 * nd + ALPHA_ * bhi(xq.z));
    o.w = pack2(a6 * nd + ALPHA_ * blo(xq.w), a7 * nd + ALPHA_ * bhi(xq.w));
    ((uint4*)aggb)[(size_t)gi * 16 + lane] = o;
}

// ---------------- MFMA conv: rst_r @ W'_r (+bias-init) [+leaky] summed over r ----------------
template<int LIN>
__global__ __launch_bounds__(256) void conv_mfma_kernel(
    const unsigned short* __restrict__ aggb,   // [R][N][128] bf16
    const unsigned short* __restrict__ WtG,    // [R][128][128] bf16, [n][k]
    const float* __restrict__ bias,            // [R,128]
    const unsigned short* __restrict__ WlT,    // [64][128] bf16 (LIN)
    const float* __restrict__ blin,            // [64] (LIN)
    unsigned short* __restrict__ houtb,        // h1b (LIN=0)
    float* __restrict__ outf)                  // out [N,64] (LIN=1)
{
    __shared__ unsigned short WtL[DD * 136];   // 34816 B, stride 136 bf16 (17 uint4)
    uint4* WtL4 = (uint4*)WtL;
    const int tid  = threadIdx.x;
    const int wave = tid >> 6;
    const int lane = tid & 63;
    const int l15  = lane & 15;
    const int q    = lane >> 4;                // 0..3
    const int blockRow = blockIdx.x * 64;
    const int row0 = blockRow + wave * 16;
    const int arow = min(row0 + l15, NN - 1);  // A-frag row (clamped)

    f32x4 o[8];
    if (LIN) {
        #pragma unroll
        for (int ct = 0; ct < 8; ++ct) {
            const int col = ct * 16 + l15;
            const float bv = (bias[col] + bias[DD + col] + bias[2 * DD + col]) * (1.0f / 3.0f);
            o[ct] = (f32x4){bv, bv, bv, bv};
        }
    } else {
        #pragma unroll
        for (int ct = 0; ct < 8; ++ct) o[ct] = (f32x4){0.f, 0.f, 0.f, 0.f};
    }

    for (int r = 0; r < RR; ++r) {
        __syncthreads();
        const uint4* wg = (const uint4*)(WtG + (size_t)r * DD * DD);
        for (int i = tid; i < DD * 16; i += 256)
            WtL4[(i >> 4) * 17 + (i & 15)] = wg[i];
        __syncthreads();

        short8 a[4];
        const uint4* ap = (const uint4*)aggb + ((size_t)r * NN + arow) * 16 + q;
        #pragma unroll
        for (int ks = 0; ks < 4; ++ks)
            a[ks] = __builtin_bit_cast(short8, ap[ks * 4]);

        #pragma unroll
        for (int ct = 0; ct < 8; ++ct) {
            f32x4 acc;
            if (LIN) {
                acc = o[ct];
            } else {
                const float bv = bias[r * DD + ct * 16 + l15];
                acc = (f32x4){bv, bv, bv, bv};
            }
            const int nrow = ct * 16 + l15;
            #pragma unroll
            for (int ks = 0; ks < 4; ++ks) {
                const short8 b = __builtin_bit_cast(short8, WtL4[nrow * 17 + ks * 4 + q]);
                acc = __builtin_amdgcn_mfma_f32_16x16x32_bf16(a[ks], b, acc, 0, 0, 0);
            }
            if (LIN) {
                o[ct] = acc;
            } else {
                #pragma unroll
                for (int e = 0; e < 4; ++e) {
                    float v = acc[e];
                    v = v >= 0.f ? v : SLOPE_ * v;
                    o[ct][e] += v * (1.0f / 3.0f);
                }
            }
        }
    }

    __syncthreads();
    unsigned short* tile = WtL;                // rows 0..63, stride 136
    #pragma unroll
    for (int ct = 0; ct < 8; ++ct) {
        const int col = ct * 16 + l15;
        #pragma unroll
        for (int e = 0; e < 4; ++e) {
            const int lrow = wave * 16 + q * 4 + e;
            tile[lrow * 136 + col] = f2b(o[ct][e]);
        }
    }
    if (LIN) {
        uint4* wl4 = WtL4 + 64 * 17;
        const uint4* wg = (const uint4*)WlT;
        for (int i = tid; i < OUTD * 16; i += 256)
            wl4[(i >> 4) * 17 + (i & 15)] = wg[i];
    }
    __syncthreads();

    if (!LIN) {
        for (int i = tid; i < 64 * 16; i += 256) {
            const int lrow = i >> 4, c = i & 15;
            const int grow = blockRow + lrow;
            if (grow < NN)
                ((uint4*)houtb)[(size_t)grow * 16 + c] = WtL4[lrow * 17 + c];
        }
    } else {
        short8 a2[4];
        const int lrow = wave * 16 + l15;
        #pragma unroll
        for (int ks = 0; ks < 4; ++ks)
            a2[ks] = __builtin_bit_cast(short8, WtL4[lrow * 17 + ks * 4 + q]);
        #pragma unroll
        for (int ct = 0; ct < 4; ++ct) {
            const int col = ct * 16 + l15;
            const float bv = blin[col];
            f32x4 acc = (f32x4){bv, bv, bv, bv};
            #pragma unroll
            for (int ks = 0; ks < 4; ++ks) {
                const short8 b = __builtin_bit_cast(short8, WtL4[(64 + col) * 17 + ks * 4 + q]);
                acc = __builtin_amdgcn_mfma_f32_16x16x32_bf16(a2[ks], b, acc, 0, 0, 0);
            }
            #pragma unroll
            for (int e = 0; e < 4; ++e) {
                const int grow = row0 + q * 4 + e;
                if (grow < NN) outf[(size_t)grow * OUTD + col] = acc[e];
            }
        }
    }
}

extern "C" void kernel_launch(void* const* d_in, const int* in_sizes, int n_in,
                              void* d_out, int out_size, void* d_ws, size_t ws_size,
                              hipStream_t stream)
{
    const float* x    = (const float*)d_in[0];
    const int*   src  = (const int*)  d_in[1];
    const int*   dst  = (const int*)  d_in[2];
    const float* W1   = (const float*)d_in[3];
    const float* b1   = (const float*)d_in[4];
    const float* W2   = (const float*)d_in[5];
    const float* b2   = (const float*)d_in[6];
    const float* Wlin = (const float*)d_in[7];
    const float* blin = (const float*)d_in[8];
    float* out = (float*)d_out;

    // ws layout (4B units): bcnt_d[3*NBK] | bcnt_s[3*NBK] | dego_r[3N] | degi_r[3N] |
    //   off_g[3N] | cnt_g[3N] | pad[2] | pairs_d[3*NBK*CAP] | pairs_s(u16) |
    //   xb(bf16 N*D) | h1b(bf16 N*D) | aggb(bf16 3*N*D) | Wt1 | Wt2 | WlT    ~= 85 MB
    int*   bcnt_d  = (int*)d_ws;
    int*   bcnt_s  = bcnt_d + RR * NBK;
    float* dego_r  = (float*)(bcnt_s + RR * NBK);
    float* degi_r  = dego_r + RR * NN;
    int*   off_g   = (int*)(degi_r + RR * NN);
    int*   cnt_g   = off_g + RR * NN;
    int*   pairs_d = cnt_g + RR * NN + 2;    // +2 -> 16B alignment downstream
    unsigned short* pairs_s = (unsigned short*)(pairs_d + (size_t)RR * NBK * CAP);
    unsigned short* xb   = pairs_s + (size_t)RR * NBK * CAPB;
    unsigned short* h1b  = xb + (size_t)NN * DD;
    unsigned short* aggb = h1b + (size_t)NN * DD;
    unsigned short* Wt1  = aggb + (size_t)RR * NN * DD;
    unsigned short* Wt2  = Wt1 + RR * DD * DD;
    unsigned short* WlT  = Wt2 + RR * DD * DD;

    hipMemsetAsync(bcnt_d, 0, (size_t)2 * RR * NBK * sizeof(int), stream);

    const int gemm_blocks = (NN + 63) / 64;

    // ---- graph preprocessing (once; same graph both layers) ----
    bin_kernel<<<2 * RR * NCH, 256, 0, stream>>>(src, dst, bcnt_d, bcnt_s, pairs_d, pairs_s);
    dego_setup_kernel<<<RR * NBK + SETUPB, 256, 0, stream>>>(
        pairs_s, bcnt_s, dego_r, x, xb, W1, W2, Wlin, Wt1, Wt2, WlT);
    sort_kernel<<<RR * NBK, 256, 0, stream>>>(
        pairs_d, bcnt_d, dego_r, off_g, cnt_g, degi_r);

    // ---- conv1: h1b = bf16( mean_r leaky( rst_r @ W1'_r + b1_r ) ) ----
    pull_all_kernel<<<RR * NPB, 256, 0, stream>>>(
        xb, xb, pairs_d, off_g, cnt_g, degi_r, aggb);
    conv_mfma_kernel<0><<<gemm_blocks, 256, 0, stream>>>(
        aggb, Wt1, b1, nullptr, nullptr, h1b, nullptr);

    // ---- conv2 (+ fused final linear): out = ( sum_r rst_r @ (W2'_r/3) + mean b2 ) @ Wlin + blin ----
    pull_all_kernel<<<RR * NPB, 256, 0, stream>>>(
        h1b, xb, pairs_d, off_g, cnt_g, degi_r, aggb);
    conv_mfma_kernel<1><<<gemm_blocks, 256, 0, stream>>>(
        aggb, Wt2, b2, WlT, blin, nullptr, out);
}